// Round 9
// baseline (646.173 us; speedup 1.0000x reference)
//
#include <hip/hip_runtime.h>
#include <hip/hip_fp16.h>
#include <math.h>

#define N_ENT 100000
#define N_EDGE 500000
#define N_REL 200
// DIM=64, HEADS=4, HD=256

typedef short bf16x8 __attribute__((ext_vector_type(8)));
typedef _Float16 f16x8 __attribute__((ext_vector_type(8)));
typedef float f32x4 __attribute__((ext_vector_type(4)));

// tanh via exp2-based __expf + 1-ulp v_rcp: 1 - 2/(e^(2x)+1).
// ~5 instrs vs ~14 for the IEEE-divide form. Error ~1e-7 rel — harmless.
__device__ __forceinline__ float fast_tanh(float x) {
    float xc = fminf(x, 15.f);
    float e = __expf(2.f * xc);
    return 1.f - 2.f * __builtin_amdgcn_rcpf(e + 1.f);
}

__device__ __forceinline__ unsigned short f2bf(float f) {
    unsigned u = __float_as_uint(f);
    unsigned r = u + 0x7FFF + ((u >> 16) & 1);   // round-to-nearest-even
    return (unsigned short)(r >> 16);
}

__device__ __forceinline__ uint2 pack_half4(const float4 v) {
    __half2 lo = __floats2half2_rn(v.x, v.y);
    __half2 hi = __floats2half2_rn(v.z, v.w);
    uint2 r;
    r.x = *reinterpret_cast<const unsigned int*>(&lo);
    r.y = *reinterpret_cast<const unsigned int*>(&hi);
    return r;
}

__device__ __forceinline__ float4 unpack_half4(uint2 u) {
    __half2 lo = *reinterpret_cast<const __half2*>(&u.x);
    __half2 hi = *reinterpret_cast<const __half2*>(&u.y);
    float2 a = __half22float2(lo);
    float2 b = __half22float2(hi);
    return make_float4(a.x, a.y, b.x, b.y);
}

// ---------------------------------------------------------------------------
// Convert entity_embed fp32 -> bf16 (RNE), vectorized 4/thread.
__global__ __launch_bounds__(256) void cvt_emb_kernel(
    const float* __restrict__ in, unsigned short* __restrict__ out, int nquads)
{
    for (int i = blockIdx.x * 256 + threadIdx.x; i < nquads; i += gridDim.x * 256) {
        float4 v = ((const float4*)in)[i];
        ushort4 o;
        o.x = f2bf(v.x); o.y = f2bf(v.y); o.z = f2bf(v.z); o.w = f2bf(v.w);
        ((ushort4*)out)[i] = o;
    }
}

// ---------------------------------------------------------------------------
// Build wT[(mat*256+col)*64 + k] = bf16(W_mat[k*256+col]). 32768 elems.
__global__ __launch_bounds__(256) void cvt_wT_kernel(
    const float* __restrict__ W0, const float* __restrict__ W1,
    unsigned short* __restrict__ wT)
{
    int idx = blockIdx.x * 256 + threadIdx.x;     // 0..32767
    if (idx >= 2 * 256 * 64) return;
    int mat = idx >> 14;
    int rem = idx & 16383;
    int col = rem >> 6;
    int k   = rem & 63;
    const float* W = (mat == 0) ? W0 : W1;
    wT[idx] = f2bf(W[k * 256 + col]);
}

// ---------------------------------------------------------------------------
// Build woT[d*256 + k] = fp16(Wo[k*64+d]). 16384 elems.
__global__ __launch_bounds__(256) void cvt_woT_kernel(
    const float* __restrict__ Wo, __half* __restrict__ woT)
{
    int idx = blockIdx.x * 256 + threadIdx.x;     // 0..16383
    if (idx >= 64 * 256) return;
    int d = idx >> 8;
    int k = idx & 255;
    woT[idx] = __float2half(Wo[k * 64 + d]);
}

// ---------------------------------------------------------------------------
// MFMA attention projections for h and t (shared A = entity embed).
// Wave owns 16 entity rows. C layout (HW-verified): col=lane&15,
// row=(lane>>4)*4+reg.
__global__ __launch_bounds__(256) void proj_mfma_kernel(
    const unsigned short* __restrict__ emb_bf,   // [N][64] bf16
    const unsigned short* __restrict__ wT,       // [2*256][64] bf16
    const float* __restrict__ att0, const float* __restrict__ att1,
    float* __restrict__ p0, float* __restrict__ p1, int nrows)
{
    const int wv   = threadIdx.x >> 6;
    const int lane = threadIdx.x & 63;
    const int r4   = lane >> 4;        // k-group / C-row-quad selector
    const int cl   = lane & 15;        // A-row / B-col / C-col selector
    const int rowbase = blockIdx.x * 64 + wv * 16;

    int ra = min(rowbase + cl, nrows - 1);
    bf16x8 a0 = *(const bf16x8*)(emb_bf + (size_t)ra * 64 + 8 * r4);
    bf16x8 a1 = *(const bf16x8*)(emb_bf + (size_t)ra * 64 + 8 * r4 + 32);

#pragma unroll
    for (int mat = 0; mat < 2; ++mat) {
        const float* att = (mat == 0) ? att0 : att1;
        float* p         = (mat == 0) ? p0 : p1;
        float pacc[4][4];   // [head][j]
#pragma unroll
        for (int head = 0; head < 4; ++head) {
            float vsum[4] = {0.f, 0.f, 0.f, 0.f};
#pragma unroll
            for (int sub = 0; sub < 4; ++sub) {
                int col = head * 64 + sub * 16 + cl;
                const unsigned short* wp =
                    wT + ((size_t)(mat * 256 + col)) * 64 + 8 * r4;
                bf16x8 b0 = *(const bf16x8*)(wp);
                bf16x8 b1 = *(const bf16x8*)(wp + 32);
                f32x4 c = {0.f, 0.f, 0.f, 0.f};
                c = __builtin_amdgcn_mfma_f32_16x16x32_bf16(a0, b0, c, 0, 0, 0);
                c = __builtin_amdgcn_mfma_f32_16x16x32_bf16(a1, b1, c, 0, 0, 0);
                float av = att[head * 64 + sub * 16 + cl];
#pragma unroll
                for (int j = 0; j < 4; ++j)
                    vsum[j] = fmaf(fast_tanh(c[j]), av, vsum[j]);
            }
#pragma unroll
            for (int j = 0; j < 4; ++j) {
                float v = vsum[j];
                v += __shfl_xor(v, 1, 64);
                v += __shfl_xor(v, 2, 64);
                v += __shfl_xor(v, 4, 64);
                v += __shfl_xor(v, 8, 64);
                pacc[head][j] = v;
            }
        }
        if (cl == 0) {
#pragma unroll
            for (int j = 0; j < 4; ++j) {
                int row = rowbase + r4 * 4 + j;
                if (row < nrows) {
                    *(float4*)(p + (size_t)row * 4) = make_float4(
                        pacc[0][j], pacc[1][j], pacc[2][j], pacc[3][j]);
                }
            }
        }
    }
}

// ---------------------------------------------------------------------------
// VALU projection for relations (only 200 rows — not worth MFMA).
__global__ __launch_bounds__(256) void proj_gemm_kernel(
    const float* __restrict__ emb,     // [nrows,64]
    const float* __restrict__ W0,      // [64,256]
    const float* __restrict__ att0,    // [4,64]
    float* __restrict__ p0,            // [nrows,4]
    int nrows)
{
    __shared__ float e_lds[64][68];
    __shared__ float w0_lds[64][64];
    __shared__ float red[4][4][64];    // [wave][head][er+16*i]

    const int t    = threadIdx.x;
    const int wv   = t >> 6;
    const int lane = t & 63;
    const int er   = t & 15;
    const int d0   = (t >> 4) * 4;
    const int base = blockIdx.x * 64;

#pragma unroll
    for (int i = 0; i < 4; ++i) {
        int f = t + 256 * i;
        int row = f >> 4, c4 = f & 15;
        int gr = min(base + row, nrows - 1);
        float4 v = *(const float4*)(emb + (size_t)gr * 64 + 4 * c4);
        *(float4*)&e_lds[row][4 * c4] = v;
    }

    float p0s[4][4];

    for (int head = 0; head < 4; ++head) {
        {
            int k0 = t >> 4, c4 = t & 15;
#pragma unroll
            for (int kk = 0; kk < 4; ++kk) {
                int k = k0 + 16 * kk;
                *(float4*)&w0_lds[k][4 * c4] =
                    *(const float4*)(W0 + (size_t)k * 256 + head * 64 + 4 * c4);
            }
        }
        __syncthreads();

        float acc0[4][4] = {};
        for (int k4 = 0; k4 < 16; ++k4) {
            float4 z0 = *(const float4*)&e_lds[er +  0][4 * k4];
            float4 z1 = *(const float4*)&e_lds[er + 16][4 * k4];
            float4 z2 = *(const float4*)&e_lds[er + 32][4 * k4];
            float4 z3 = *(const float4*)&e_lds[er + 48][4 * k4];
            const float zr[4][4] = {
                {z0.x, z0.y, z0.z, z0.w},
                {z1.x, z1.y, z1.z, z1.w},
                {z2.x, z2.y, z2.z, z2.w},
                {z3.x, z3.y, z3.z, z3.w}};
#pragma unroll
            for (int jj = 0; jj < 4; ++jj) {
                float4 w0v = *(const float4*)&w0_lds[4 * k4 + jj][d0];
#pragma unroll
                for (int i = 0; i < 4; ++i) {
                    float zj = zr[i][jj];
                    acc0[i][0] = fmaf(zj, w0v.x, acc0[i][0]);
                    acc0[i][1] = fmaf(zj, w0v.y, acc0[i][1]);
                    acc0[i][2] = fmaf(zj, w0v.z, acc0[i][2]);
                    acc0[i][3] = fmaf(zj, w0v.w, acc0[i][3]);
                }
            }
        }

        float4 av0 = *(const float4*)(att0 + head * 64 + d0);
#pragma unroll
        for (int i = 0; i < 4; ++i) {
            float v = fast_tanh(acc0[i][0]) * av0.x
                    + fast_tanh(acc0[i][1]) * av0.y
                    + fast_tanh(acc0[i][2]) * av0.z
                    + fast_tanh(acc0[i][3]) * av0.w;
            v += __shfl_xor(v, 16, 64);
            v += __shfl_xor(v, 32, 64);
            p0s[head][i] = v;
        }
        __syncthreads();
    }

    if (lane < 16) {
#pragma unroll
        for (int h = 0; h < 4; ++h)
#pragma unroll
            for (int i = 0; i < 4; ++i)
                red[wv][h][lane + 16 * i] = p0s[h][i];
    }
    __syncthreads();
    if (t < 64) {
        int row = base + t;
        if (row < nrows) {
            float4 pv;
            pv.x = red[0][0][t] + red[1][0][t] + red[2][0][t] + red[3][0][t];
            pv.y = red[0][1][t] + red[1][1][t] + red[2][1][t] + red[3][1][t];
            pv.z = red[0][2][t] + red[1][2][t] + red[2][2][t] + red[3][2][t];
            pv.w = red[0][3][t] + red[1][3][t] + red[2][3][t] + red[3][3][t];
            *(float4*)(p0 + (size_t)row * 4) = pv;
        }
    }
}

// ---------------------------------------------------------------------------
// Degree histogram: 1 atomic per edge.
__global__ __launch_bounds__(256) void hist_kernel(
    const int* __restrict__ eidx, int* __restrict__ counts)
{
    int e = blockIdx.x * 256 + threadIdx.x;
    if (e >= N_EDGE) return;
    atomicAdd(&counts[eidx[e]], 1);
}

// ---------------------------------------------------------------------------
// Exclusive scan of counts[N_ENT] -> row_start[N_ENT+1]. Single block.
__global__ __launch_bounds__(1024) void scan_kernel(
    const int* __restrict__ counts, int* __restrict__ row_start)
{
    __shared__ int wsum[16];
    __shared__ int carry_s;
    const int lane = threadIdx.x & 63;
    const int wid  = threadIdx.x >> 6;
    if (threadIdx.x == 0) carry_s = 0;
    __syncthreads();
    for (int base = 0; base < N_ENT; base += 4096) {
        int i0 = base + (int)threadIdx.x * 4;
        int4 v = make_int4(0, 0, 0, 0);
        if (i0 + 3 < N_ENT) v = *(const int4*)(counts + i0);
        else {
            if (i0 + 0 < N_ENT) v.x = counts[i0 + 0];
            if (i0 + 1 < N_ENT) v.y = counts[i0 + 1];
            if (i0 + 2 < N_ENT) v.z = counts[i0 + 2];
            if (i0 + 3 < N_ENT) v.w = counts[i0 + 3];
        }
        int s1 = v.x + v.y, s2 = s1 + v.z, tsum = s2 + v.w;
        int incl = tsum;
#pragma unroll
        for (int off = 1; off < 64; off <<= 1) {
            int t = __shfl_up(incl, off, 64);
            if (lane >= off) incl += t;
        }
        if (lane == 63) wsum[wid] = incl;
        __syncthreads();                              // A
        int wave_off = 0;
#pragma unroll
        for (int w = 0; w < 16; ++w)
            wave_off += (w < wid) ? wsum[w] : 0;
        int carry = carry_s;
        int excl = carry + wave_off + (incl - tsum);
        if (i0 + 3 < N_ENT) {
            *(int4*)(row_start + i0) = make_int4(excl, excl + v.x, excl + s1, excl + s2);
        } else {
            if (i0 + 0 < N_ENT) row_start[i0 + 0] = excl;
            if (i0 + 1 < N_ENT) row_start[i0 + 1] = excl + v.x;
            if (i0 + 2 < N_ENT) row_start[i0 + 2] = excl + s1;
            if (i0 + 3 < N_ENT) row_start[i0 + 3] = excl + s2;
        }
        __syncthreads();                              // B
        if (threadIdx.x == 1023) carry_s = carry + wave_off + incl;
    }
    __syncthreads();
    if (threadIdx.x == 0) row_start[N_ENT] = carry_s;
}

// ---------------------------------------------------------------------------
// Per-edge: compute exp(leaky(score)) directly and scatter RAW exp into CSR.
__global__ __launch_bounds__(256) void scatter_score_kernel(
    const int* __restrict__ eidx, const int* __restrict__ etype,
    const float* __restrict__ ph, const float* __restrict__ pt,
    const float* __restrict__ pr,
    const int* __restrict__ row_start, int* __restrict__ cursor,
    int* __restrict__ csr_col, float* __restrict__ csr_a)
{
    int e = blockIdx.x * 256 + threadIdx.x;
    if (e >= N_EDGE) return;
    int hn = eidx[e];
    int tn = eidx[N_EDGE + e];
    int r  = etype[e];
    float4 a = *(const float4*)(ph + (size_t)hn * 4);
    float4 b = *(const float4*)(pt + (size_t)tn * 4);
    float4 c = *(const float4*)(pr + (size_t)r * 4);
    float s0 = a.x + b.x + c.x;
    float s1 = a.y + b.y + c.y;
    float s2 = a.z + b.z + c.z;
    float s3 = a.w + b.w + c.w;
    s0 = s0 >= 0.f ? s0 : 0.01f * s0;
    s1 = s1 >= 0.f ? s1 : 0.01f * s1;
    s2 = s2 >= 0.f ? s2 : 0.01f * s2;
    s3 = s3 >= 0.f ? s3 : 0.01f * s3;
    float4 ev = make_float4(__expf(s0), __expf(s1), __expf(s2), __expf(s3));
    int pos = row_start[hn] + atomicAdd(&cursor[hn], 1);
    csr_col[pos] = tn;
    *(float4*)(csr_a + (size_t)pos * 4) = ev;
}

// ---------------------------------------------------------------------------
// Row-wise softmax normalize: csr_a[p][h] *= 0.9 / (sum_row csr_a[.][h] + eps)
__global__ __launch_bounds__(256) void normalize_kernel(
    const int* __restrict__ row_start, float* __restrict__ csr_a)
{
    const int wid  = threadIdx.x >> 6;
    const int lane = threadIdx.x & 63;
    const int n = blockIdx.x * 4 + wid;
    if (n >= N_ENT) return;
    const int s   = row_start[n];
    const int end = row_start[n + 1];
    const int nf  = (end - s) * 4;          // floats in this row

    float sum = 0.f;
    for (int f = lane; f < nf; f += 64)
        sum += csr_a[(size_t)s * 4 + f];
#pragma unroll
    for (int off = 4; off < 64; off <<= 1)
        sum += __shfl_xor(sum, off, 64);
    float scale = 0.9f * __builtin_amdgcn_rcpf(sum + 1e-16f);
    for (int f = lane; f < nf; f += 64)
        csr_a[(size_t)s * 4 + f] *= scale;
}

// ---------------------------------------------------------------------------
// SpMM step. Wave per entity; lane handles cols 4*lane..+3, h = lane/16.
// Metadata via broadcast loads (no DS/shfl on the critical path); 8
// independent accumulators / gathers in flight. OOB edges handled by
// index-clamp + zero multiplier (no divergent branches).
template <bool IN_HALF, bool OUT_HALF>
__global__ __launch_bounds__(256) void spmm_kernel(
    const void* __restrict__ Zin_v, const float* __restrict__ emb,
    const int* __restrict__ row_start, const int* __restrict__ csr_col,
    const float* __restrict__ csr_a, void* __restrict__ Zout_v)
{
    const int wave = threadIdx.x >> 6;
    const int lane = threadIdx.x & 63;
    const int n = blockIdx.x * 4 + wave;
    const int h = lane >> 4;
    const __half* Zin_h = (const __half*)Zin_v;

    const float4* e4 = (const float4*)emb;   // [N][16]
    float4 zi = e4[(size_t)n * 16 + (lane & 15)];
    float4 acc[8];
    acc[0] = make_float4(0.1f * zi.x, 0.1f * zi.y, 0.1f * zi.z, 0.1f * zi.w);
#pragma unroll
    for (int u = 1; u < 8; ++u) acc[u] = make_float4(0.f, 0.f, 0.f, 0.f);

    const int s   = row_start[n];
    const int end = row_start[n + 1];

    for (int p = s; p < end; p += 8) {
#pragma unroll
        for (int u = 0; u < 8; ++u) {
            int pe = p + u;
            int pc = min(pe, end - 1);
            int c  = csr_col[pc];                         // broadcast load
            float a = csr_a[(size_t)pc * 4 + h];          // 4-addr broadcast
            a = (pe < end) ? a : 0.f;
            float4 z;
            if (IN_HALF) {
                uint2 uu = *(const uint2*)(Zin_h + (size_t)c * 256 + 4 * lane);
                z = unpack_half4(uu);
            } else {
                z = *(const float4*)(emb + (size_t)c * 64 + 4 * (lane & 15));
            }
            acc[u].x = fmaf(a, z.x, acc[u].x);
            acc[u].y = fmaf(a, z.y, acc[u].y);
            acc[u].z = fmaf(a, z.z, acc[u].z);
            acc[u].w = fmaf(a, z.w, acc[u].w);
        }
    }
#pragma unroll
    for (int u = 1; u < 8; ++u) {
        acc[0].x += acc[u].x;
        acc[0].y += acc[u].y;
        acc[0].z += acc[u].z;
        acc[0].w += acc[u].w;
    }

    if (OUT_HALF)
        *(uint2*)((__half*)Zout_v + (size_t)n * 256 + 4 * lane) = pack_half4(acc[0]);
    else
        *(float4*)((float*)Zout_v + (size_t)n * 256 + 4 * lane) = acc[0];
}

// ---------------------------------------------------------------------------
// out[100000,64] = Z5[100000,256](fp16) @ Wo[256,64] via MFMA f16.
__global__ __launch_bounds__(256) void outproj_mfma_kernel(
    const __half* __restrict__ Z,      // [N][256] fp16
    const __half* __restrict__ woT,    // [64][256] fp16 (d-major)
    float* __restrict__ out)           // [N][64]
{
    const int wv   = threadIdx.x >> 6;
    const int lane = threadIdx.x & 63;
    const int cl   = lane & 15;
    const int r4   = lane >> 4;
    const int rowbase = blockIdx.x * 64 + wv * 16;

    int ra = min(rowbase + cl, N_ENT - 1);
    const _Float16* zp = (const _Float16*)(Z + (size_t)ra * 256);
    f16x8 a[8];
#pragma unroll
    for (int ks = 0; ks < 8; ++ks)
        a[ks] = *(const f16x8*)(zp + ks * 32 + 8 * r4);

    const _Float16* wp = (const _Float16*)woT;
#pragma unroll
    for (int st = 0; st < 4; ++st) {
        f32x4 c = {0.f, 0.f, 0.f, 0.f};
        const _Float16* wcol = wp + (size_t)(st * 16 + cl) * 256 + 8 * r4;
#pragma unroll
        for (int ks = 0; ks < 8; ++ks) {
            f16x8 b = *(const f16x8*)(wcol + ks * 32);
            c = __builtin_amdgcn_mfma_f32_16x16x32_f16(a[ks], b, c, 0, 0, 0);
        }
#pragma unroll
        for (int j = 0; j < 4; ++j) {
            int row = rowbase + r4 * 4 + j;
            if (row < N_ENT)
                out[(size_t)row * 64 + st * 16 + cl] = c[j];
        }
    }
}

// ---------------------------------------------------------------------------
extern "C" void kernel_launch(void* const* d_in, const int* in_sizes, int n_in,
                              void* d_out, int out_size, void* d_ws, size_t ws_size,
                              hipStream_t stream)
{
    const float* entity = (const float*)d_in[0];
    const float* rel    = (const float*)d_in[1];
    const float* W_h    = (const float*)d_in[2];
    const float* W_t    = (const float*)d_in[3];
    const float* W_r    = (const float*)d_in[4];
    const float* att_h  = (const float*)d_in[5];
    const float* att_t  = (const float*)d_in[6];
    const float* att_r  = (const float*)d_in[7];
    const float* W_o    = (const float*)d_in[8];
    const int*   eidx   = (const int*)d_in[9];   // [2,E]
    const int*   etype  = (const int*)d_in[10];  // [E]
    float* out = (float*)d_out;

    char* ws = (char*)d_ws;
    size_t off = 0;
    auto alloc = [&](size_t bytes) -> void* {
        void* p = ws + off;
        off += (bytes + 255) & ~(size_t)255;
        return p;
    };
    float* p_h      = (float*)alloc((size_t)N_ENT * 4 * 4);
    float* p_t      = (float*)alloc((size_t)N_ENT * 4 * 4);
    float* p_r      = (float*)alloc((size_t)N_REL * 4 * 4);
    int*   counts   = (int*)alloc((size_t)N_ENT * 4);
    int*   row_start= (int*)alloc(((size_t)N_ENT + 1) * 4);
    int*   cursor   = (int*)alloc((size_t)N_ENT * 4);
    int*   csr_col  = (int*)alloc((size_t)N_EDGE * 4);
    float* csr_a    = (float*)alloc((size_t)N_EDGE * 4 * 4);
    __half* Zh_a    = (__half*)alloc((size_t)N_ENT * 256 * 2);
    __half* Zh_b    = (__half*)alloc((size_t)N_ENT * 256 * 2);
    unsigned short* emb_bf = (unsigned short*)alloc((size_t)N_ENT * 64 * 2);
    unsigned short* wT     = (unsigned short*)alloc((size_t)2 * 256 * 64 * 2);
    __half* woT     = (__half*)alloc((size_t)64 * 256 * 2);

    hipMemsetAsync(counts, 0, (size_t)N_ENT * 4, stream);
    hipMemsetAsync(cursor, 0, (size_t)N_ENT * 4, stream);

    // bf16/fp16 prep
    cvt_emb_kernel<<<2048, 256, 0, stream>>>(entity, emb_bf, N_ENT * 64 / 4);
    cvt_wT_kernel<<<(2 * 256 * 64 + 255) / 256, 256, 0, stream>>>(W_h, W_t, wT);
    cvt_woT_kernel<<<(64 * 256 + 255) / 256, 256, 0, stream>>>(W_o, woT);

    // projections: h/t via MFMA, relations via VALU
    proj_mfma_kernel<<<(N_ENT + 63) / 64, 256, 0, stream>>>(
        emb_bf, wT, att_h, att_t, p_h, p_t, N_ENT);
    proj_gemm_kernel<<<(N_REL + 63) / 64, 256, 0, stream>>>(
        rel, W_r, att_r, p_r, N_REL);

    hist_kernel<<<(N_EDGE + 255) / 256, 256, 0, stream>>>(eidx, counts);
    scan_kernel<<<1, 1024, 0, stream>>>(counts, row_start);
    scatter_score_kernel<<<(N_EDGE + 255) / 256, 256, 0, stream>>>(
        eidx, etype, p_h, p_t, p_r, row_start, cursor, csr_col, csr_a);
    normalize_kernel<<<(N_ENT + 3) / 4, 256, 0, stream>>>(row_start, csr_a);

    // power iteration: Z1..Z5, all fp16 intermediates incl. Z5
    spmm_kernel<false, true ><<<N_ENT / 4, 256, 0, stream>>>(nullptr, entity, row_start, csr_col, csr_a, Zh_b);
    spmm_kernel<true,  true ><<<N_ENT / 4, 256, 0, stream>>>(Zh_b, entity, row_start, csr_col, csr_a, Zh_a);
    spmm_kernel<true,  true ><<<N_ENT / 4, 256, 0, stream>>>(Zh_a, entity, row_start, csr_col, csr_a, Zh_b);
    spmm_kernel<true,  true ><<<N_ENT / 4, 256, 0, stream>>>(Zh_b, entity, row_start, csr_col, csr_a, Zh_a);
    spmm_kernel<true,  true ><<<N_ENT / 4, 256, 0, stream>>>(Zh_a, entity, row_start, csr_col, csr_a, Zh_b);

    // output projection via MFMA f16
    outproj_mfma_kernel<<<(N_ENT + 63) / 64, 256, 0, stream>>>(Zh_b, woT, out);
}

// Round 10
// 439.428 us; speedup vs baseline: 1.4705x; 1.4705x over previous
//
#include <hip/hip_runtime.h>
#include <hip/hip_fp16.h>
#include <math.h>

#define N_ENT 100000
#define N_EDGE 500000
#define N_REL 200
// DIM=64, HEADS=4, HD=256

typedef short bf16x8 __attribute__((ext_vector_type(8)));
typedef _Float16 f16x8 __attribute__((ext_vector_type(8)));
typedef float f32x4 __attribute__((ext_vector_type(4)));

// tanh via __expf + 1-ulp v_rcp: 1 - 2/(e^(2x)+1).
__device__ __forceinline__ float fast_tanh(float x) {
    float xc = fminf(x, 15.f);
    float e = __expf(2.f * xc);
    return 1.f - 2.f * __builtin_amdgcn_rcpf(e + 1.f);
}

__device__ __forceinline__ unsigned short f2bf(float f) {
    unsigned u = __float_as_uint(f);
    unsigned r = u + 0x7FFF + ((u >> 16) & 1);   // round-to-nearest-even
    return (unsigned short)(r >> 16);
}

__device__ __forceinline__ uint2 pack_half4(const float4 v) {
    __half2 lo = __floats2half2_rn(v.x, v.y);
    __half2 hi = __floats2half2_rn(v.z, v.w);
    uint2 r;
    r.x = *reinterpret_cast<const unsigned int*>(&lo);
    r.y = *reinterpret_cast<const unsigned int*>(&hi);
    return r;
}

__device__ __forceinline__ float4 unpack_half4(uint2 u) {
    __half2 lo = *reinterpret_cast<const __half2*>(&u.x);
    __half2 hi = *reinterpret_cast<const __half2*>(&u.y);
    float2 a = __half22float2(lo);
    float2 b = __half22float2(hi);
    return make_float4(a.x, a.y, b.x, b.y);
}

// ---------------------------------------------------------------------------
__global__ __launch_bounds__(256) void cvt_emb_kernel(
    const float* __restrict__ in, unsigned short* __restrict__ out, int nquads)
{
    for (int i = blockIdx.x * 256 + threadIdx.x; i < nquads; i += gridDim.x * 256) {
        float4 v = ((const float4*)in)[i];
        ushort4 o;
        o.x = f2bf(v.x); o.y = f2bf(v.y); o.z = f2bf(v.z); o.w = f2bf(v.w);
        ((ushort4*)out)[i] = o;
    }
}

// ---------------------------------------------------------------------------
__global__ __launch_bounds__(256) void cvt_wT_kernel(
    const float* __restrict__ W0, const float* __restrict__ W1,
    unsigned short* __restrict__ wT)
{
    int idx = blockIdx.x * 256 + threadIdx.x;     // 0..32767
    if (idx >= 2 * 256 * 64) return;
    int mat = idx >> 14;
    int rem = idx & 16383;
    int col = rem >> 6;
    int k   = rem & 63;
    const float* W = (mat == 0) ? W0 : W1;
    wT[idx] = f2bf(W[k * 256 + col]);
}

// ---------------------------------------------------------------------------
__global__ __launch_bounds__(256) void cvt_woT_kernel(
    const float* __restrict__ Wo, __half* __restrict__ woT)
{
    int idx = blockIdx.x * 256 + threadIdx.x;     // 0..16383
    if (idx >= 64 * 256) return;
    int d = idx >> 8;
    int k = idx & 255;
    woT[idx] = __float2half(Wo[k * 64 + d]);
}

// ---------------------------------------------------------------------------
// MFMA attention projections for h and t.
__global__ __launch_bounds__(256) void proj_mfma_kernel(
    const unsigned short* __restrict__ emb_bf,   // [N][64] bf16
    const unsigned short* __restrict__ wT,       // [2*256][64] bf16
    const float* __restrict__ att0, const float* __restrict__ att1,
    float* __restrict__ p0, float* __restrict__ p1, int nrows)
{
    const int wv   = threadIdx.x >> 6;
    const int lane = threadIdx.x & 63;
    const int r4   = lane >> 4;
    const int cl   = lane & 15;
    const int rowbase = blockIdx.x * 64 + wv * 16;

    int ra = min(rowbase + cl, nrows - 1);
    bf16x8 a0 = *(const bf16x8*)(emb_bf + (size_t)ra * 64 + 8 * r4);
    bf16x8 a1 = *(const bf16x8*)(emb_bf + (size_t)ra * 64 + 8 * r4 + 32);

#pragma unroll
    for (int mat = 0; mat < 2; ++mat) {
        const float* att = (mat == 0) ? att0 : att1;
        float* p         = (mat == 0) ? p0 : p1;
        float pacc[4][4];   // [head][j]
#pragma unroll
        for (int head = 0; head < 4; ++head) {
            float vsum[4] = {0.f, 0.f, 0.f, 0.f};
#pragma unroll
            for (int sub = 0; sub < 4; ++sub) {
                int col = head * 64 + sub * 16 + cl;
                const unsigned short* wp =
                    wT + ((size_t)(mat * 256 + col)) * 64 + 8 * r4;
                bf16x8 b0 = *(const bf16x8*)(wp);
                bf16x8 b1 = *(const bf16x8*)(wp + 32);
                f32x4 c = {0.f, 0.f, 0.f, 0.f};
                c = __builtin_amdgcn_mfma_f32_16x16x32_bf16(a0, b0, c, 0, 0, 0);
                c = __builtin_amdgcn_mfma_f32_16x16x32_bf16(a1, b1, c, 0, 0, 0);
                float av = att[head * 64 + sub * 16 + cl];
#pragma unroll
                for (int j = 0; j < 4; ++j)
                    vsum[j] = fmaf(fast_tanh(c[j]), av, vsum[j]);
            }
#pragma unroll
            for (int j = 0; j < 4; ++j) {
                float v = vsum[j];
                v += __shfl_xor(v, 1, 64);
                v += __shfl_xor(v, 2, 64);
                v += __shfl_xor(v, 4, 64);
                v += __shfl_xor(v, 8, 64);
                pacc[head][j] = v;
            }
        }
        if (cl == 0) {
#pragma unroll
            for (int j = 0; j < 4; ++j) {
                int row = rowbase + r4 * 4 + j;
                if (row < nrows) {
                    *(float4*)(p + (size_t)row * 4) = make_float4(
                        pacc[0][j], pacc[1][j], pacc[2][j], pacc[3][j]);
                }
            }
        }
    }
}

// ---------------------------------------------------------------------------
// VALU projection for relations (only 200 rows).
__global__ __launch_bounds__(256) void proj_gemm_kernel(
    const float* __restrict__ emb,
    const float* __restrict__ W0,
    const float* __restrict__ att0,
    float* __restrict__ p0,
    int nrows)
{
    __shared__ float e_lds[64][68];
    __shared__ float w0_lds[64][64];
    __shared__ float red[4][4][64];

    const int t    = threadIdx.x;
    const int wv   = t >> 6;
    const int lane = t & 63;
    const int er   = t & 15;
    const int d0   = (t >> 4) * 4;
    const int base = blockIdx.x * 64;

#pragma unroll
    for (int i = 0; i < 4; ++i) {
        int f = t + 256 * i;
        int row = f >> 4, c4 = f & 15;
        int gr = min(base + row, nrows - 1);
        float4 v = *(const float4*)(emb + (size_t)gr * 64 + 4 * c4);
        *(float4*)&e_lds[row][4 * c4] = v;
    }

    float p0s[4][4];

    for (int head = 0; head < 4; ++head) {
        {
            int k0 = t >> 4, c4 = t & 15;
#pragma unroll
            for (int kk = 0; kk < 4; ++kk) {
                int k = k0 + 16 * kk;
                *(float4*)&w0_lds[k][4 * c4] =
                    *(const float4*)(W0 + (size_t)k * 256 + head * 64 + 4 * c4);
            }
        }
        __syncthreads();

        float acc0[4][4] = {};
        for (int k4 = 0; k4 < 16; ++k4) {
            float4 z0 = *(const float4*)&e_lds[er +  0][4 * k4];
            float4 z1 = *(const float4*)&e_lds[er + 16][4 * k4];
            float4 z2 = *(const float4*)&e_lds[er + 32][4 * k4];
            float4 z3 = *(const float4*)&e_lds[er + 48][4 * k4];
            const float zr[4][4] = {
                {z0.x, z0.y, z0.z, z0.w},
                {z1.x, z1.y, z1.z, z1.w},
                {z2.x, z2.y, z2.z, z2.w},
                {z3.x, z3.y, z3.z, z3.w}};
#pragma unroll
            for (int jj = 0; jj < 4; ++jj) {
                float4 w0v = *(const float4*)&w0_lds[4 * k4 + jj][d0];
#pragma unroll
                for (int i = 0; i < 4; ++i) {
                    float zj = zr[i][jj];
                    acc0[i][0] = fmaf(zj, w0v.x, acc0[i][0]);
                    acc0[i][1] = fmaf(zj, w0v.y, acc0[i][1]);
                    acc0[i][2] = fmaf(zj, w0v.z, acc0[i][2]);
                    acc0[i][3] = fmaf(zj, w0v.w, acc0[i][3]);
                }
            }
        }

        float4 av0 = *(const float4*)(att0 + head * 64 + d0);
#pragma unroll
        for (int i = 0; i < 4; ++i) {
            float v = fast_tanh(acc0[i][0]) * av0.x
                    + fast_tanh(acc0[i][1]) * av0.y
                    + fast_tanh(acc0[i][2]) * av0.z
                    + fast_tanh(acc0[i][3]) * av0.w;
            v += __shfl_xor(v, 16, 64);
            v += __shfl_xor(v, 32, 64);
            p0s[head][i] = v;
        }
        __syncthreads();
    }

    if (lane < 16) {
#pragma unroll
        for (int h = 0; h < 4; ++h)
#pragma unroll
            for (int i = 0; i < 4; ++i)
                red[wv][h][lane + 16 * i] = p0s[h][i];
    }
    __syncthreads();
    if (t < 64) {
        int row = base + t;
        if (row < nrows) {
            float4 pv;
            pv.x = red[0][0][t] + red[1][0][t] + red[2][0][t] + red[3][0][t];
            pv.y = red[0][1][t] + red[1][1][t] + red[2][1][t] + red[3][1][t];
            pv.z = red[0][2][t] + red[1][2][t] + red[2][2][t] + red[3][2][t];
            pv.w = red[0][3][t] + red[1][3][t] + red[2][3][t] + red[3][3][t];
            *(float4*)(p0 + (size_t)row * 4) = pv;
        }
    }
}

// ---------------------------------------------------------------------------
__global__ __launch_bounds__(256) void hist_kernel(
    const int* __restrict__ eidx, int* __restrict__ counts)
{
    int e = blockIdx.x * 256 + threadIdx.x;
    if (e >= N_EDGE) return;
    atomicAdd(&counts[eidx[e]], 1);
}

// ---------------------------------------------------------------------------
__global__ __launch_bounds__(1024) void scan_kernel(
    const int* __restrict__ counts, int* __restrict__ row_start)
{
    __shared__ int wsum[16];
    __shared__ int carry_s;
    const int lane = threadIdx.x & 63;
    const int wid  = threadIdx.x >> 6;
    if (threadIdx.x == 0) carry_s = 0;
    __syncthreads();
    for (int base = 0; base < N_ENT; base += 4096) {
        int i0 = base + (int)threadIdx.x * 4;
        int4 v = make_int4(0, 0, 0, 0);
        if (i0 + 3 < N_ENT) v = *(const int4*)(counts + i0);
        else {
            if (i0 + 0 < N_ENT) v.x = counts[i0 + 0];
            if (i0 + 1 < N_ENT) v.y = counts[i0 + 1];
            if (i0 + 2 < N_ENT) v.z = counts[i0 + 2];
            if (i0 + 3 < N_ENT) v.w = counts[i0 + 3];
        }
        int s1 = v.x + v.y, s2 = s1 + v.z, tsum = s2 + v.w;
        int incl = tsum;
#pragma unroll
        for (int off = 1; off < 64; off <<= 1) {
            int t = __shfl_up(incl, off, 64);
            if (lane >= off) incl += t;
        }
        if (lane == 63) wsum[wid] = incl;
        __syncthreads();                              // A
        int wave_off = 0;
#pragma unroll
        for (int w = 0; w < 16; ++w)
            wave_off += (w < wid) ? wsum[w] : 0;
        int carry = carry_s;
        int excl = carry + wave_off + (incl - tsum);
        if (i0 + 3 < N_ENT) {
            *(int4*)(row_start + i0) = make_int4(excl, excl + v.x, excl + s1, excl + s2);
        } else {
            if (i0 + 0 < N_ENT) row_start[i0 + 0] = excl;
            if (i0 + 1 < N_ENT) row_start[i0 + 1] = excl + v.x;
            if (i0 + 2 < N_ENT) row_start[i0 + 2] = excl + s1;
            if (i0 + 3 < N_ENT) row_start[i0 + 3] = excl + s2;
        }
        __syncthreads();                              // B
        if (threadIdx.x == 1023) carry_s = carry + wave_off + incl;
    }
    __syncthreads();
    if (threadIdx.x == 0) row_start[N_ENT] = carry_s;
}

// ---------------------------------------------------------------------------
__global__ __launch_bounds__(256) void scatter_score_kernel(
    const int* __restrict__ eidx, const int* __restrict__ etype,
    const float* __restrict__ ph, const float* __restrict__ pt,
    const float* __restrict__ pr,
    const int* __restrict__ row_start, int* __restrict__ cursor,
    int* __restrict__ csr_col, float* __restrict__ csr_a)
{
    int e = blockIdx.x * 256 + threadIdx.x;
    if (e >= N_EDGE) return;
    int hn = eidx[e];
    int tn = eidx[N_EDGE + e];
    int r  = etype[e];
    float4 a = *(const float4*)(ph + (size_t)hn * 4);
    float4 b = *(const float4*)(pt + (size_t)tn * 4);
    float4 c = *(const float4*)(pr + (size_t)r * 4);
    float s0 = a.x + b.x + c.x;
    float s1 = a.y + b.y + c.y;
    float s2 = a.z + b.z + c.z;
    float s3 = a.w + b.w + c.w;
    s0 = s0 >= 0.f ? s0 : 0.01f * s0;
    s1 = s1 >= 0.f ? s1 : 0.01f * s1;
    s2 = s2 >= 0.f ? s2 : 0.01f * s2;
    s3 = s3 >= 0.f ? s3 : 0.01f * s3;
    float4 ev = make_float4(__expf(s0), __expf(s1), __expf(s2), __expf(s3));
    int pos = row_start[hn] + atomicAdd(&cursor[hn], 1);
    csr_col[pos] = tn;
    *(float4*)(csr_a + (size_t)pos * 4) = ev;
}

// ---------------------------------------------------------------------------
__global__ __launch_bounds__(256) void normalize_kernel(
    const int* __restrict__ row_start, float* __restrict__ csr_a)
{
    const int wid  = threadIdx.x >> 6;
    const int lane = threadIdx.x & 63;
    const int n = blockIdx.x * 4 + wid;
    if (n >= N_ENT) return;
    const int s   = row_start[n];
    const int end = row_start[n + 1];
    const int nf  = (end - s) * 4;

    float sum = 0.f;
    for (int f = lane; f < nf; f += 64)
        sum += csr_a[(size_t)s * 4 + f];
#pragma unroll
    for (int off = 4; off < 64; off <<= 1)
        sum += __shfl_xor(sum, off, 64);
    float scale = 0.9f * __builtin_amdgcn_rcpf(sum + 1e-16f);
    for (int f = lane; f < nf; f += 64)
        csr_a[(size_t)s * 4 + f] *= scale;
}

// ---------------------------------------------------------------------------
// SpMM row body (round-8 proven structure): lane-parallel metadata fetch,
// shfl distribute, exact-count gathers, 4 independent accumulators.
template <bool IN_HALF>
__device__ __forceinline__ float4 spmm_row(
    int n, int lane, int h,
    const __half* __restrict__ Zin_h, const float* __restrict__ emb,
    const int* __restrict__ row_start, const int* __restrict__ csr_col,
    const float* __restrict__ csr_a)
{
    const float4* e4 = (const float4*)emb;   // [N][16]
    float4 zi = e4[(size_t)n * 16 + (lane & 15)];
    float4 acc0 = make_float4(0.1f * zi.x, 0.1f * zi.y, 0.1f * zi.z, 0.1f * zi.w);
    float4 acc1 = make_float4(0.f, 0.f, 0.f, 0.f);
    float4 acc2 = make_float4(0.f, 0.f, 0.f, 0.f);
    float4 acc3 = make_float4(0.f, 0.f, 0.f, 0.f);

    const int s   = row_start[n];
    const int end = row_start[n + 1];

    auto zrow = [&](int c) -> float4 {
        if (IN_HALF) {
            uint2 u = *(const uint2*)(Zin_h + (size_t)c * 256 + 4 * lane);
            return unpack_half4(u);
        } else {
            return *(const float4*)(emb + (size_t)c * 64 + 4 * (lane & 15));
        }
    };
    auto fma4 = [](float4& acc, float a, const float4& z) {
        acc.x = fmaf(a, z.x, acc.x);
        acc.y = fmaf(a, z.y, acc.y);
        acc.z = fmaf(a, z.z, acc.z);
        acc.w = fmaf(a, z.w, acc.w);
    };

    for (int b = s; b < end; b += 16) {
        const int nb = min(16, end - b);
        int   cl = (lane < nb) ? csr_col[b + lane] : 0;
        float al = (lane < nb * 4) ? csr_a[(size_t)b * 4 + lane] : 0.f;

        int j = 0;
        for (; j + 4 <= nb; j += 4) {
            int c0 = __shfl(cl, j + 0, 64);
            int c1 = __shfl(cl, j + 1, 64);
            int c2 = __shfl(cl, j + 2, 64);
            int c3 = __shfl(cl, j + 3, 64);
            float a0 = __shfl(al, (j + 0) * 4 + h, 64);
            float a1 = __shfl(al, (j + 1) * 4 + h, 64);
            float a2 = __shfl(al, (j + 2) * 4 + h, 64);
            float a3 = __shfl(al, (j + 3) * 4 + h, 64);
            float4 za = zrow(c0);
            float4 zb = zrow(c1);
            float4 zc = zrow(c2);
            float4 zd = zrow(c3);
            fma4(acc0, a0, za);
            fma4(acc1, a1, zb);
            fma4(acc2, a2, zc);
            fma4(acc3, a3, zd);
        }
        if (j + 0 < nb) {
            int c = __shfl(cl, j + 0, 64);
            float a = __shfl(al, (j + 0) * 4 + h, 64);
            fma4(acc0, a, zrow(c));
        }
        if (j + 1 < nb) {
            int c = __shfl(cl, j + 1, 64);
            float a = __shfl(al, (j + 1) * 4 + h, 64);
            fma4(acc1, a, zrow(c));
        }
        if (j + 2 < nb) {
            int c = __shfl(cl, j + 2, 64);
            float a = __shfl(al, (j + 2) * 4 + h, 64);
            fma4(acc2, a, zrow(c));
        }
    }
    acc0.x += acc1.x + acc2.x + acc3.x;
    acc0.y += acc1.y + acc2.y + acc3.y;
    acc0.z += acc1.z + acc2.z + acc3.z;
    acc0.w += acc1.w + acc2.w + acc3.w;
    return acc0;
}

// ---------------------------------------------------------------------------
// Standalone SpMM step (iterations 1..4).
template <bool IN_HALF>
__global__ __launch_bounds__(256) void spmm_kernel(
    const void* __restrict__ Zin_v, const float* __restrict__ emb,
    const int* __restrict__ row_start, const int* __restrict__ csr_col,
    const float* __restrict__ csr_a, void* __restrict__ Zout_v)
{
    const int wave = threadIdx.x >> 6;
    const int lane = threadIdx.x & 63;
    const int n = blockIdx.x * 4 + wave;
    const int h = lane >> 4;
    float4 acc = spmm_row<IN_HALF>(n, lane, h, (const __half*)Zin_v, emb,
                                   row_start, csr_col, csr_a);
    *(uint2*)((__half*)Zout_v + (size_t)n * 256 + 4 * lane) = pack_half4(acc);
}

// ---------------------------------------------------------------------------
// Fused: 5th SpMM + output projection. Block = 16 rows.
// Phase 1: wave wv computes rows base+wv*4 .. +3 -> fp16 LDS tile [16][264].
// Phase 2: wave wv takes output col-strip st=wv: 8x mfma f16 from LDS A-frags
// and L2-hot woT B-frags; writes out directly. Skips Z5 write+read (~100 MB).
__global__ __launch_bounds__(256) void spmm_out_fused_kernel(
    const __half* __restrict__ Zin, const float* __restrict__ emb,
    const int* __restrict__ row_start, const int* __restrict__ csr_col,
    const float* __restrict__ csr_a,
    const __half* __restrict__ woT,    // [64][256] fp16 (d-major)
    float* __restrict__ out)           // [N][64]
{
    __shared__ _Float16 zl[16][264];   // pad 256->264 halves (16B) for banks
    const int wv   = threadIdx.x >> 6;
    const int lane = threadIdx.x & 63;
    const int h    = lane >> 4;
    const int base = blockIdx.x * 16;

#pragma unroll
    for (int rr = 0; rr < 4; ++rr) {
        int n = base + wv * 4 + rr;
        float4 acc = spmm_row<true>(n, lane, h, Zin, emb,
                                    row_start, csr_col, csr_a);
        *(uint2*)&zl[wv * 4 + rr][4 * lane] = pack_half4(acc);
    }
    __syncthreads();

    // phase 2: MFMA out-projection, col strip st = wv
    const int cl = lane & 15;
    const int r4 = lane >> 4;
    f16x8 a[8];
#pragma unroll
    for (int ks = 0; ks < 8; ++ks)
        a[ks] = *(const f16x8*)&zl[cl][ks * 32 + 8 * r4];

    const _Float16* wcol = (const _Float16*)woT + (size_t)(wv * 16 + cl) * 256 + 8 * r4;
    f32x4 c = {0.f, 0.f, 0.f, 0.f};
#pragma unroll
    for (int ks = 0; ks < 8; ++ks) {
        f16x8 b = *(const f16x8*)(wcol + ks * 32);
        c = __builtin_amdgcn_mfma_f32_16x16x32_f16(a[ks], b, c, 0, 0, 0);
    }
#pragma unroll
    for (int j = 0; j < 4; ++j) {
        int row = base + r4 * 4 + j;
        out[(size_t)row * 64 + wv * 16 + cl] = c[j];
    }
}

// ---------------------------------------------------------------------------
extern "C" void kernel_launch(void* const* d_in, const int* in_sizes, int n_in,
                              void* d_out, int out_size, void* d_ws, size_t ws_size,
                              hipStream_t stream)
{
    const float* entity = (const float*)d_in[0];
    const float* rel    = (const float*)d_in[1];
    const float* W_h    = (const float*)d_in[2];
    const float* W_t    = (const float*)d_in[3];
    const float* W_r    = (const float*)d_in[4];
    const float* att_h  = (const float*)d_in[5];
    const float* att_t  = (const float*)d_in[6];
    const float* att_r  = (const float*)d_in[7];
    const float* W_o    = (const float*)d_in[8];
    const int*   eidx   = (const int*)d_in[9];   // [2,E]
    const int*   etype  = (const int*)d_in[10];  // [E]
    float* out = (float*)d_out;

    char* ws = (char*)d_ws;
    size_t off = 0;
    auto alloc = [&](size_t bytes) -> void* {
        void* p = ws + off;
        off += (bytes + 255) & ~(size_t)255;
        return p;
    };
    float* p_h      = (float*)alloc((size_t)N_ENT * 4 * 4);
    float* p_t      = (float*)alloc((size_t)N_ENT * 4 * 4);
    float* p_r      = (float*)alloc((size_t)N_REL * 4 * 4);
    int*   counts   = (int*)alloc((size_t)N_ENT * 4);
    int*   row_start= (int*)alloc(((size_t)N_ENT + 1) * 4);
    int*   cursor   = (int*)alloc((size_t)N_ENT * 4);
    int*   csr_col  = (int*)alloc((size_t)N_EDGE * 4);
    float* csr_a    = (float*)alloc((size_t)N_EDGE * 4 * 4);
    __half* Zh_a    = (__half*)alloc((size_t)N_ENT * 256 * 2);
    __half* Zh_b    = (__half*)alloc((size_t)N_ENT * 256 * 2);
    unsigned short* emb_bf = (unsigned short*)alloc((size_t)N_ENT * 64 * 2);
    unsigned short* wT     = (unsigned short*)alloc((size_t)2 * 256 * 64 * 2);
    __half* woT     = (__half*)alloc((size_t)64 * 256 * 2);

    hipMemsetAsync(counts, 0, (size_t)N_ENT * 4, stream);
    hipMemsetAsync(cursor, 0, (size_t)N_ENT * 4, stream);

    // bf16/fp16 prep
    cvt_emb_kernel<<<2048, 256, 0, stream>>>(entity, emb_bf, N_ENT * 64 / 4);
    cvt_wT_kernel<<<(2 * 256 * 64 + 255) / 256, 256, 0, stream>>>(W_h, W_t, wT);
    cvt_woT_kernel<<<(64 * 256 + 255) / 256, 256, 0, stream>>>(W_o, woT);

    // projections: h/t via MFMA, relations via VALU
    proj_mfma_kernel<<<(N_ENT + 63) / 64, 256, 0, stream>>>(
        emb_bf, wT, att_h, att_t, p_h, p_t, N_ENT);
    proj_gemm_kernel<<<(N_REL + 63) / 64, 256, 0, stream>>>(
        rel, W_r, att_r, p_r, N_REL);

    hist_kernel<<<(N_EDGE + 255) / 256, 256, 0, stream>>>(eidx, counts);
    scan_kernel<<<1, 1024, 0, stream>>>(counts, row_start);
    scatter_score_kernel<<<(N_EDGE + 255) / 256, 256, 0, stream>>>(
        eidx, etype, p_h, p_t, p_r, row_start, cursor, csr_col, csr_a);
    normalize_kernel<<<(N_ENT + 3) / 4, 256, 0, stream>>>(row_start, csr_a);

    // power iteration: Z1..Z4 standalone, Z5 fused with output projection
    spmm_kernel<false><<<N_ENT / 4, 256, 0, stream>>>(nullptr, entity, row_start, csr_col, csr_a, Zh_b);
    spmm_kernel<true ><<<N_ENT / 4, 256, 0, stream>>>(Zh_b, entity, row_start, csr_col, csr_a, Zh_a);
    spmm_kernel<true ><<<N_ENT / 4, 256, 0, stream>>>(Zh_a, entity, row_start, csr_col, csr_a, Zh_b);
    spmm_kernel<true ><<<N_ENT / 4, 256, 0, stream>>>(Zh_b, entity, row_start, csr_col, csr_a, Zh_a);
    spmm_out_fused_kernel<<<N_ENT / 16, 256, 0, stream>>>(
        Zh_a, entity, row_start, csr_col, csr_a, woT, out);
}

// Round 11
// 415.918 us; speedup vs baseline: 1.5536x; 1.0565x over previous
//
#include <hip/hip_runtime.h>
#include <hip/hip_fp16.h>
#include <math.h>

#define N_ENT 100000
#define N_EDGE 500000
#define N_REL 200
// DIM=64, HEADS=4, HD=256

typedef short bf16x8 __attribute__((ext_vector_type(8)));
typedef _Float16 f16x8 __attribute__((ext_vector_type(8)));
typedef float f32x4 __attribute__((ext_vector_type(4)));

__device__ __forceinline__ float fast_tanh(float x) {
    float xc = fminf(x, 15.f);
    float e = __expf(2.f * xc);
    return 1.f - 2.f * __builtin_amdgcn_rcpf(e + 1.f);
}

__device__ __forceinline__ unsigned short f2bf(float f) {
    unsigned u = __float_as_uint(f);
    unsigned r = u + 0x7FFF + ((u >> 16) & 1);   // RNE
    return (unsigned short)(r >> 16);
}

__device__ __forceinline__ uint2 pack_half4(const float4 v) {
    __half2 lo = __floats2half2_rn(v.x, v.y);
    __half2 hi = __floats2half2_rn(v.z, v.w);
    uint2 r;
    r.x = *reinterpret_cast<const unsigned int*>(&lo);
    r.y = *reinterpret_cast<const unsigned int*>(&hi);
    return r;
}

__device__ __forceinline__ float4 unpack_half4(uint2 u) {
    __half2 lo = *reinterpret_cast<const __half2*>(&u.x);
    __half2 hi = *reinterpret_cast<const __half2*>(&u.y);
    float2 a = __half22float2(lo);
    float2 b = __half22float2(hi);
    return make_float4(a.x, a.y, b.x, b.y);
}

// ---------------------------------------------------------------------------
// Merged prep: [0,1954) hist, [1954,4002) cvt_emb, [4002,4130) cvt_wT,
// [4130,4194) cvt_woT. All independent jobs, one dispatch.
#define HIST_B 1954
#define EMB_B  2048
#define WT_B   128
#define WOT_B  64
__global__ __launch_bounds__(256) void prep_kernel(
    const float* __restrict__ entity, unsigned short* __restrict__ emb_bf,
    const float* __restrict__ W0, const float* __restrict__ W1,
    unsigned short* __restrict__ wT,
    const float* __restrict__ Wo, __half* __restrict__ woT,
    const int* __restrict__ eidx, int* __restrict__ counts)
{
    int bid = blockIdx.x;
    if (bid < HIST_B) {
        int e = bid * 256 + threadIdx.x;
        if (e < N_EDGE) atomicAdd(&counts[eidx[e]], 1);
    } else if (bid < HIST_B + EMB_B) {
        int b = bid - HIST_B;
        const int nquads = N_ENT * 64 / 4;
        for (int i = b * 256 + threadIdx.x; i < nquads; i += EMB_B * 256) {
            float4 v = ((const float4*)entity)[i];
            ushort4 o;
            o.x = f2bf(v.x); o.y = f2bf(v.y); o.z = f2bf(v.z); o.w = f2bf(v.w);
            ((ushort4*)emb_bf)[i] = o;
        }
    } else if (bid < HIST_B + EMB_B + WT_B) {
        int idx = (bid - HIST_B - EMB_B) * 256 + threadIdx.x;   // 0..32767
        int mat = idx >> 14;
        int rem = idx & 16383;
        int col = rem >> 6;
        int k   = rem & 63;
        const float* W = (mat == 0) ? W0 : W1;
        wT[idx] = f2bf(W[k * 256 + col]);
    } else {
        int idx = (bid - HIST_B - EMB_B - WT_B) * 256 + threadIdx.x;  // 0..16383
        int d = idx >> 8;
        int k = idx & 255;
        woT[idx] = __float2half(Wo[k * 64 + d]);
    }
}

// ---------------------------------------------------------------------------
// MFMA attention projection, ONE mat per block (mat split across grid for 2x
// TLP). Wave owns 16 entity rows. C layout (HW-verified): col=lane&15,
// row=(lane>>4)*4+reg.
__global__ __launch_bounds__(256) void proj_mfma_kernel(
    const unsigned short* __restrict__ emb_bf,   // [N][64] bf16
    const unsigned short* __restrict__ wT,       // [2*256][64] bf16
    const float* __restrict__ att0, const float* __restrict__ att1,
    float* __restrict__ p0, float* __restrict__ p1, int nrows, int nb)
{
    const int mat = (blockIdx.x >= nb) ? 1 : 0;
    const int rb  = blockIdx.x - mat * nb;
    const float* att = (mat == 0) ? att0 : att1;
    float* p         = (mat == 0) ? p0 : p1;
    const unsigned short* wbase = wT + (size_t)mat * 256 * 64;

    const int wv   = threadIdx.x >> 6;
    const int lane = threadIdx.x & 63;
    const int r4   = lane >> 4;
    const int cl   = lane & 15;
    const int rowbase = rb * 64 + wv * 16;

    int ra = min(rowbase + cl, nrows - 1);
    bf16x8 a0 = *(const bf16x8*)(emb_bf + (size_t)ra * 64 + 8 * r4);
    bf16x8 a1 = *(const bf16x8*)(emb_bf + (size_t)ra * 64 + 8 * r4 + 32);

    float pacc[4][4];   // [head][j]
#pragma unroll
    for (int head = 0; head < 4; ++head) {
        float vsum[4] = {0.f, 0.f, 0.f, 0.f};
#pragma unroll
        for (int sub = 0; sub < 4; ++sub) {
            int col = head * 64 + sub * 16 + cl;
            const unsigned short* wp = wbase + (size_t)col * 64 + 8 * r4;
            bf16x8 b0 = *(const bf16x8*)(wp);
            bf16x8 b1 = *(const bf16x8*)(wp + 32);
            f32x4 c = {0.f, 0.f, 0.f, 0.f};
            c = __builtin_amdgcn_mfma_f32_16x16x32_bf16(a0, b0, c, 0, 0, 0);
            c = __builtin_amdgcn_mfma_f32_16x16x32_bf16(a1, b1, c, 0, 0, 0);
            float av = att[head * 64 + sub * 16 + cl];
#pragma unroll
            for (int j = 0; j < 4; ++j)
                vsum[j] = fmaf(fast_tanh(c[j]), av, vsum[j]);
        }
#pragma unroll
        for (int j = 0; j < 4; ++j) {
            float v = vsum[j];
            v += __shfl_xor(v, 1, 64);
            v += __shfl_xor(v, 2, 64);
            v += __shfl_xor(v, 4, 64);
            v += __shfl_xor(v, 8, 64);
            pacc[head][j] = v;
        }
    }
    if (cl == 0) {
#pragma unroll
        for (int j = 0; j < 4; ++j) {
            int row = rowbase + r4 * 4 + j;
            if (row < nrows) {
                *(float4*)(p + (size_t)row * 4) = make_float4(
                    pacc[0][j], pacc[1][j], pacc[2][j], pacc[3][j]);
            }
        }
    }
}

// ---------------------------------------------------------------------------
// VALU projection for relations (only 200 rows).
__global__ __launch_bounds__(256) void proj_gemm_kernel(
    const float* __restrict__ emb,
    const float* __restrict__ W0,
    const float* __restrict__ att0,
    float* __restrict__ p0,
    int nrows)
{
    __shared__ float e_lds[64][68];
    __shared__ float w0_lds[64][64];
    __shared__ float red[4][4][64];

    const int t    = threadIdx.x;
    const int wv   = t >> 6;
    const int lane = t & 63;
    const int er   = t & 15;
    const int d0   = (t >> 4) * 4;
    const int base = blockIdx.x * 64;

#pragma unroll
    for (int i = 0; i < 4; ++i) {
        int f = t + 256 * i;
        int row = f >> 4, c4 = f & 15;
        int gr = min(base + row, nrows - 1);
        float4 v = *(const float4*)(emb + (size_t)gr * 64 + 4 * c4);
        *(float4*)&e_lds[row][4 * c4] = v;
    }

    float p0s[4][4];

    for (int head = 0; head < 4; ++head) {
        {
            int k0 = t >> 4, c4 = t & 15;
#pragma unroll
            for (int kk = 0; kk < 4; ++kk) {
                int k = k0 + 16 * kk;
                *(float4*)&w0_lds[k][4 * c4] =
                    *(const float4*)(W0 + (size_t)k * 256 + head * 64 + 4 * c4);
            }
        }
        __syncthreads();

        float acc0[4][4] = {};
        for (int k4 = 0; k4 < 16; ++k4) {
            float4 z0 = *(const float4*)&e_lds[er +  0][4 * k4];
            float4 z1 = *(const float4*)&e_lds[er + 16][4 * k4];
            float4 z2 = *(const float4*)&e_lds[er + 32][4 * k4];
            float4 z3 = *(const float4*)&e_lds[er + 48][4 * k4];
            const float zr[4][4] = {
                {z0.x, z0.y, z0.z, z0.w},
                {z1.x, z1.y, z1.z, z1.w},
                {z2.x, z2.y, z2.z, z2.w},
                {z3.x, z3.y, z3.z, z3.w}};
#pragma unroll
            for (int jj = 0; jj < 4; ++jj) {
                float4 w0v = *(const float4*)&w0_lds[4 * k4 + jj][d0];
#pragma unroll
                for (int i = 0; i < 4; ++i) {
                    float zj = zr[i][jj];
                    acc0[i][0] = fmaf(zj, w0v.x, acc0[i][0]);
                    acc0[i][1] = fmaf(zj, w0v.y, acc0[i][1]);
                    acc0[i][2] = fmaf(zj, w0v.z, acc0[i][2]);
                    acc0[i][3] = fmaf(zj, w0v.w, acc0[i][3]);
                }
            }
        }

        float4 av0 = *(const float4*)(att0 + head * 64 + d0);
#pragma unroll
        for (int i = 0; i < 4; ++i) {
            float v = fast_tanh(acc0[i][0]) * av0.x
                    + fast_tanh(acc0[i][1]) * av0.y
                    + fast_tanh(acc0[i][2]) * av0.z
                    + fast_tanh(acc0[i][3]) * av0.w;
            v += __shfl_xor(v, 16, 64);
            v += __shfl_xor(v, 32, 64);
            p0s[head][i] = v;
        }
        __syncthreads();
    }

    if (lane < 16) {
#pragma unroll
        for (int h = 0; h < 4; ++h)
#pragma unroll
            for (int i = 0; i < 4; ++i)
                red[wv][h][lane + 16 * i] = p0s[h][i];
    }
    __syncthreads();
    if (t < 64) {
        int row = base + t;
        if (row < nrows) {
            float4 pv;
            pv.x = red[0][0][t] + red[1][0][t] + red[2][0][t] + red[3][0][t];
            pv.y = red[0][1][t] + red[1][1][t] + red[2][1][t] + red[3][1][t];
            pv.z = red[0][2][t] + red[1][2][t] + red[2][2][t] + red[3][2][t];
            pv.w = red[0][3][t] + red[1][3][t] + red[2][3][t] + red[3][3][t];
            *(float4*)(p0 + (size_t)row * 4) = pv;
        }
    }
}

// ---------------------------------------------------------------------------
__global__ __launch_bounds__(1024) void scan_kernel(
    const int* __restrict__ counts, int* __restrict__ row_start)
{
    __shared__ int wsum[16];
    __shared__ int carry_s;
    const int lane = threadIdx.x & 63;
    const int wid  = threadIdx.x >> 6;
    if (threadIdx.x == 0) carry_s = 0;
    __syncthreads();
    for (int base = 0; base < N_ENT; base += 4096) {
        int i0 = base + (int)threadIdx.x * 4;
        int4 v = make_int4(0, 0, 0, 0);
        if (i0 + 3 < N_ENT) v = *(const int4*)(counts + i0);
        else {
            if (i0 + 0 < N_ENT) v.x = counts[i0 + 0];
            if (i0 + 1 < N_ENT) v.y = counts[i0 + 1];
            if (i0 + 2 < N_ENT) v.z = counts[i0 + 2];
            if (i0 + 3 < N_ENT) v.w = counts[i0 + 3];
        }
        int s1 = v.x + v.y, s2 = s1 + v.z, tsum = s2 + v.w;
        int incl = tsum;
#pragma unroll
        for (int off = 1; off < 64; off <<= 1) {
            int t = __shfl_up(incl, off, 64);
            if (lane >= off) incl += t;
        }
        if (lane == 63) wsum[wid] = incl;
        __syncthreads();                              // A
        int wave_off = 0;
#pragma unroll
        for (int w = 0; w < 16; ++w)
            wave_off += (w < wid) ? wsum[w] : 0;
        int carry = carry_s;
        int excl = carry + wave_off + (incl - tsum);
        if (i0 + 3 < N_ENT) {
            *(int4*)(row_start + i0) = make_int4(excl, excl + v.x, excl + s1, excl + s2);
        } else {
            if (i0 + 0 < N_ENT) row_start[i0 + 0] = excl;
            if (i0 + 1 < N_ENT) row_start[i0 + 1] = excl + v.x;
            if (i0 + 2 < N_ENT) row_start[i0 + 2] = excl + s1;
            if (i0 + 3 < N_ENT) row_start[i0 + 3] = excl + s2;
        }
        __syncthreads();                              // B
        if (threadIdx.x == 1023) carry_s = carry + wave_off + incl;
    }
    __syncthreads();
    if (threadIdx.x == 0) row_start[N_ENT] = carry_s;
}

// ---------------------------------------------------------------------------
__global__ __launch_bounds__(256) void scatter_score_kernel(
    const int* __restrict__ eidx, const int* __restrict__ etype,
    const float* __restrict__ ph, const float* __restrict__ pt,
    const float* __restrict__ pr,
    const int* __restrict__ row_start, int* __restrict__ cursor,
    int* __restrict__ csr_col, float* __restrict__ csr_a)
{
    int e = blockIdx.x * 256 + threadIdx.x;
    if (e >= N_EDGE) return;
    int hn = eidx[e];
    int tn = eidx[N_EDGE + e];
    int r  = etype[e];
    float4 a = *(const float4*)(ph + (size_t)hn * 4);
    float4 b = *(const float4*)(pt + (size_t)tn * 4);
    float4 c = *(const float4*)(pr + (size_t)r * 4);
    float s0 = a.x + b.x + c.x;
    float s1 = a.y + b.y + c.y;
    float s2 = a.z + b.z + c.z;
    float s3 = a.w + b.w + c.w;
    s0 = s0 >= 0.f ? s0 : 0.01f * s0;
    s1 = s1 >= 0.f ? s1 : 0.01f * s1;
    s2 = s2 >= 0.f ? s2 : 0.01f * s2;
    s3 = s3 >= 0.f ? s3 : 0.01f * s3;
    float4 ev = make_float4(__expf(s0), __expf(s1), __expf(s2), __expf(s3));
    int pos = row_start[hn] + atomicAdd(&cursor[hn], 1);
    csr_col[pos] = tn;
    *(float4*)(csr_a + (size_t)pos * 4) = ev;
}

// ---------------------------------------------------------------------------
// Fused softmax-normalize + first SpMM. Wave per row.
// Each lane's csr_a floats all belong to head lane&3 (index = 4*edge + lane,
// stride 64) -> per-head sums via shfl_xor strides 4..32; normalized values
// written back for iters 2..5 and used directly for the emb gathers.
__global__ __launch_bounds__(256) void norm_spmm1_kernel(
    const float* __restrict__ emb,
    const int* __restrict__ row_start, const int* __restrict__ csr_col,
    float* __restrict__ csr_a, __half* __restrict__ Zout)
{
    const int wave = threadIdx.x >> 6;
    const int lane = threadIdx.x & 63;
    const int n = blockIdx.x * 4 + wave;
    const int h = lane >> 4;
    const int s   = row_start[n];
    const int end = row_start[n + 1];
    const int nf  = (end - s) * 4;

    float sum = 0.f;
    for (int f = lane; f < nf; f += 64)
        sum += csr_a[(size_t)s * 4 + f];
#pragma unroll
    for (int off = 4; off < 64; off <<= 1)
        sum += __shfl_xor(sum, off, 64);
    float scale = 0.9f * __builtin_amdgcn_rcpf(sum + 1e-16f);  // head lane&3
    // no divergence: every lane computed scale; lane h holds head h's scale.

    const float4* e4 = (const float4*)emb;   // [N][16]
    float4 zi = e4[(size_t)n * 16 + (lane & 15)];
    float4 acc0 = make_float4(0.1f * zi.x, 0.1f * zi.y, 0.1f * zi.z, 0.1f * zi.w);
    float4 acc1 = make_float4(0.f, 0.f, 0.f, 0.f);
    float4 acc2 = make_float4(0.f, 0.f, 0.f, 0.f);
    float4 acc3 = make_float4(0.f, 0.f, 0.f, 0.f);

    auto zrow = [&](int c) -> float4 {
        return *(const float4*)(emb + (size_t)c * 64 + 4 * (lane & 15));
    };
    auto fma4 = [](float4& acc, float a, const float4& z) {
        acc.x = fmaf(a, z.x, acc.x);
        acc.y = fmaf(a, z.y, acc.y);
        acc.z = fmaf(a, z.z, acc.z);
        acc.w = fmaf(a, z.w, acc.w);
    };

    for (int b = s; b < end; b += 16) {
        const int nb = min(16, end - b);
        int   cl = (lane < nb) ? csr_col[b + lane] : 0;
        float al = (lane < nb * 4) ? csr_a[(size_t)b * 4 + lane] : 0.f;
        float aln = al * scale;                        // normalize (head lane&3)
        if (lane < nb * 4) csr_a[(size_t)b * 4 + lane] = aln;   // persist

        int j = 0;
        for (; j + 4 <= nb; j += 4) {
            int c0 = __shfl(cl, j + 0, 64);
            int c1 = __shfl(cl, j + 1, 64);
            int c2 = __shfl(cl, j + 2, 64);
            int c3 = __shfl(cl, j + 3, 64);
            float a0 = __shfl(aln, (j + 0) * 4 + h, 64);
            float a1 = __shfl(aln, (j + 1) * 4 + h, 64);
            float a2 = __shfl(aln, (j + 2) * 4 + h, 64);
            float a3 = __shfl(aln, (j + 3) * 4 + h, 64);
            float4 za = zrow(c0);
            float4 zb = zrow(c1);
            float4 zc = zrow(c2);
            float4 zd = zrow(c3);
            fma4(acc0, a0, za);
            fma4(acc1, a1, zb);
            fma4(acc2, a2, zc);
            fma4(acc3, a3, zd);
        }
        if (j + 0 < nb) {
            int c = __shfl(cl, j + 0, 64);
            float a = __shfl(aln, (j + 0) * 4 + h, 64);
            fma4(acc0, a, zrow(c));
        }
        if (j + 1 < nb) {
            int c = __shfl(cl, j + 1, 64);
            float a = __shfl(aln, (j + 1) * 4 + h, 64);
            fma4(acc1, a, zrow(c));
        }
        if (j + 2 < nb) {
            int c = __shfl(cl, j + 2, 64);
            float a = __shfl(aln, (j + 2) * 4 + h, 64);
            fma4(acc2, a, zrow(c));
        }
    }
    acc0.x += acc1.x + acc2.x + acc3.x;
    acc0.y += acc1.y + acc2.y + acc3.y;
    acc0.z += acc1.z + acc2.z + acc3.z;
    acc0.w += acc1.w + acc2.w + acc3.w;
    *(uint2*)(Zout + (size_t)n * 256 + 4 * lane) = pack_half4(acc0);
}

// ---------------------------------------------------------------------------
// SpMM row body (proven round-8 structure), fp16 input.
__device__ __forceinline__ float4 spmm_row_h(
    int n, int lane, int h,
    const __half* __restrict__ Zin_h, const float* __restrict__ emb,
    const int* __restrict__ row_start, const int* __restrict__ csr_col,
    const float* __restrict__ csr_a)
{
    const float4* e4 = (const float4*)emb;   // [N][16]
    float4 zi = e4[(size_t)n * 16 + (lane & 15)];
    float4 acc0 = make_float4(0.1f * zi.x, 0.1f * zi.y, 0.1f * zi.z, 0.1f * zi.w);
    float4 acc1 = make_float4(0.f, 0.f, 0.f, 0.f);
    float4 acc2 = make_float4(0.f, 0.f, 0.f, 0.f);
    float4 acc3 = make_float4(0.f, 0.f, 0.f, 0.f);

    const int s   = row_start[n];
    const int end = row_start[n + 1];

    auto zrow = [&](int c) -> float4 {
        uint2 u = *(const uint2*)(Zin_h + (size_t)c * 256 + 4 * lane);
        return unpack_half4(u);
    };
    auto fma4 = [](float4& acc, float a, const float4& z) {
        acc.x = fmaf(a, z.x, acc.x);
        acc.y = fmaf(a, z.y, acc.y);
        acc.z = fmaf(a, z.z, acc.z);
        acc.w = fmaf(a, z.w, acc.w);
    };

    for (int b = s; b < end; b += 16) {
        const int nb = min(16, end - b);
        int   cl = (lane < nb) ? csr_col[b + lane] : 0;
        float al = (lane < nb * 4) ? csr_a[(size_t)b * 4 + lane] : 0.f;

        int j = 0;
        for (; j + 4 <= nb; j += 4) {
            int c0 = __shfl(cl, j + 0, 64);
            int c1 = __shfl(cl, j + 1, 64);
            int c2 = __shfl(cl, j + 2, 64);
            int c3 = __shfl(cl, j + 3, 64);
            float a0 = __shfl(al, (j + 0) * 4 + h, 64);
            float a1 = __shfl(al, (j + 1) * 4 + h, 64);
            float a2 = __shfl(al, (j + 2) * 4 + h, 64);
            float a3 = __shfl(al, (j + 3) * 4 + h, 64);
            float4 za = zrow(c0);
            float4 zb = zrow(c1);
            float4 zc = zrow(c2);
            float4 zd = zrow(c3);
            fma4(acc0, a0, za);
            fma4(acc1, a1, zb);
            fma4(acc2, a2, zc);
            fma4(acc3, a3, zd);
        }
        if (j + 0 < nb) {
            int c = __shfl(cl, j + 0, 64);
            float a = __shfl(al, (j + 0) * 4 + h, 64);
            fma4(acc0, a, zrow(c));
        }
        if (j + 1 < nb) {
            int c = __shfl(cl, j + 1, 64);
            float a = __shfl(al, (j + 1) * 4 + h, 64);
            fma4(acc1, a, zrow(c));
        }
        if (j + 2 < nb) {
            int c = __shfl(cl, j + 2, 64);
            float a = __shfl(al, (j + 2) * 4 + h, 64);
            fma4(acc2, a, zrow(c));
        }
    }
    acc0.x += acc1.x + acc2.x + acc3.x;
    acc0.y += acc1.y + acc2.y + acc3.y;
    acc0.z += acc1.z + acc2.z + acc3.z;
    acc0.w += acc1.w + acc2.w + acc3.w;
    return acc0;
}

// ---------------------------------------------------------------------------
// Standalone SpMM step (iterations 2..4).
__global__ __launch_bounds__(256) void spmm_kernel(
    const __half* __restrict__ Zin, const float* __restrict__ emb,
    const int* __restrict__ row_start, const int* __restrict__ csr_col,
    const float* __restrict__ csr_a, __half* __restrict__ Zout)
{
    const int wave = threadIdx.x >> 6;
    const int lane = threadIdx.x & 63;
    const int n = blockIdx.x * 4 + wave;
    const int h = lane >> 4;
    float4 acc = spmm_row_h(n, lane, h, Zin, emb, row_start, csr_col, csr_a);
    *(uint2*)(Zout + (size_t)n * 256 + 4 * lane) = pack_half4(acc);
}

// ---------------------------------------------------------------------------
// Fused: 5th SpMM + output projection. Block = 16 rows.
__global__ __launch_bounds__(256) void spmm_out_fused_kernel(
    const __half* __restrict__ Zin, const float* __restrict__ emb,
    const int* __restrict__ row_start, const int* __restrict__ csr_col,
    const float* __restrict__ csr_a,
    const __half* __restrict__ woT,    // [64][256] fp16 (d-major)
    float* __restrict__ out)           // [N][64]
{
    __shared__ _Float16 zl[16][264];
    const int wv   = threadIdx.x >> 6;
    const int lane = threadIdx.x & 63;
    const int h    = lane >> 4;
    const int base = blockIdx.x * 16;

#pragma unroll
    for (int rr = 0; rr < 4; ++rr) {
        int n = base + wv * 4 + rr;
        float4 acc = spmm_row_h(n, lane, h, Zin, emb, row_start, csr_col, csr_a);
        *(uint2*)&zl[wv * 4 + rr][4 * lane] = pack_half4(acc);
    }
    __syncthreads();

    const int cl = lane & 15;
    const int r4 = lane >> 4;
    f16x8 a[8];
#pragma unroll
    for (int ks = 0; ks < 8; ++ks)
        a[ks] = *(const f16x8*)&zl[cl][ks * 32 + 8 * r4];

    const _Float16* wcol = (const _Float16*)woT + (size_t)(wv * 16 + cl) * 256 + 8 * r4;
    f32x4 c = {0.f, 0.f, 0.f, 0.f};
#pragma unroll
    for (int ks = 0; ks < 8; ++ks) {
        f16x8 b = *(const f16x8*)(wcol + ks * 32);
        c = __builtin_amdgcn_mfma_f32_16x16x32_f16(a[ks], b, c, 0, 0, 0);
    }
#pragma unroll
    for (int j = 0; j < 4; ++j) {
        int row = base + r4 * 4 + j;
        out[(size_t)row * 64 + wv * 16 + cl] = c[j];
    }
}

// ---------------------------------------------------------------------------
extern "C" void kernel_launch(void* const* d_in, const int* in_sizes, int n_in,
                              void* d_out, int out_size, void* d_ws, size_t ws_size,
                              hipStream_t stream)
{
    const float* entity = (const float*)d_in[0];
    const float* rel    = (const float*)d_in[1];
    const float* W_h    = (const float*)d_in[2];
    const float* W_t    = (const float*)d_in[3];
    const float* W_r    = (const float*)d_in[4];
    const float* att_h  = (const float*)d_in[5];
    const float* att_t  = (const float*)d_in[6];
    const float* att_r  = (const float*)d_in[7];
    const float* W_o    = (const float*)d_in[8];
    const int*   eidx   = (const int*)d_in[9];   // [2,E]
    const int*   etype  = (const int*)d_in[10];  // [E]
    float* out = (float*)d_out;

    char* ws = (char*)d_ws;
    size_t off = 0;
    auto alloc = [&](size_t bytes) -> void* {
        void* p = ws + off;
        off += (bytes + 255) & ~(size_t)255;
        return p;
    };
    float* p_h      = (float*)alloc((size_t)N_ENT * 4 * 4);
    float* p_t      = (float*)alloc((size_t)N_ENT * 4 * 4);
    float* p_r      = (float*)alloc((size_t)N_REL * 4 * 4);
    int*   counts   = (int*)alloc((size_t)N_ENT * 4);
    int*   row_start= (int*)alloc(((size_t)N_ENT + 1) * 4);
    int*   cursor   = (int*)alloc((size_t)N_ENT * 4);
    int*   csr_col  = (int*)alloc((size_t)N_EDGE * 4);
    float* csr_a    = (float*)alloc((size_t)N_EDGE * 4 * 4);
    __half* Zh_a    = (__half*)alloc((size_t)N_ENT * 256 * 2);
    __half* Zh_b    = (__half*)alloc((size_t)N_ENT * 256 * 2);
    unsigned short* emb_bf = (unsigned short*)alloc((size_t)N_ENT * 64 * 2);
    unsigned short* wT     = (unsigned short*)alloc((size_t)2 * 256 * 64 * 2);
    __half* woT     = (__half*)alloc((size_t)64 * 256 * 2);

    hipMemsetAsync(counts, 0, (size_t)N_ENT * 4, stream);
    hipMemsetAsync(cursor, 0, (size_t)N_ENT * 4, stream);

    // merged prep: hist + bf16/fp16 conversions
    prep_kernel<<<HIST_B + EMB_B + WT_B + WOT_B, 256, 0, stream>>>(
        entity, emb_bf, W_h, W_t, wT, W_o, woT, eidx, counts);

    // projections: h/t via MFMA (mat-split grid), relations via VALU
    const int nb = (N_ENT + 63) / 64;
    proj_mfma_kernel<<<2 * nb, 256, 0, stream>>>(
        emb_bf, wT, att_h, att_t, p_h, p_t, N_ENT, nb);
    proj_gemm_kernel<<<(N_REL + 63) / 64, 256, 0, stream>>>(
        rel, W_r, att_r, p_r, N_REL);

    scan_kernel<<<1, 1024, 0, stream>>>(counts, row_start);
    scatter_score_kernel<<<(N_EDGE + 255) / 256, 256, 0, stream>>>(
        eidx, etype, p_h, p_t, p_r, row_start, cursor, csr_col, csr_a);

    // power iteration: normalize fused with Z1; Z2..Z4 standalone;
    // Z5 fused with output projection
    norm_spmm1_kernel<<<N_ENT / 4, 256, 0, stream>>>(
        entity, row_start, csr_col, csr_a, Zh_b);
    spmm_kernel<<<N_ENT / 4, 256, 0, stream>>>(Zh_b, entity, row_start, csr_col, csr_a, Zh_a);
    spmm_kernel<<<N_ENT / 4, 256, 0, stream>>>(Zh_a, entity, row_start, csr_col, csr_a, Zh_b);
    spmm_kernel<<<N_ENT / 4, 256, 0, stream>>>(Zh_b, entity, row_start, csr_col, csr_a, Zh_a);
    spmm_out_fused_kernel<<<N_ENT / 16, 256, 0, stream>>>(
        Zh_a, entity, row_start, csr_col, csr_a, woT, out);
}

// Round 12
// 405.024 us; speedup vs baseline: 1.5954x; 1.0269x over previous
//
#include <hip/hip_runtime.h>
#include <hip/hip_fp16.h>
#include <math.h>

#define N_ENT 100000
#define N_EDGE 500000
#define N_REL 200
// DIM=64, HEADS=4, HD=256

typedef short bf16x8 __attribute__((ext_vector_type(8)));
typedef _Float16 f16x8 __attribute__((ext_vector_type(8)));
typedef float f32x4 __attribute__((ext_vector_type(4)));

__device__ __forceinline__ float fast_tanh(float x) {
    float xc = fminf(x, 15.f);
    float e = __expf(2.f * xc);
    return 1.f - 2.f * __builtin_amdgcn_rcpf(e + 1.f);
}

__device__ __forceinline__ unsigned short f2bf(float f) {
    unsigned u = __float_as_uint(f);
    unsigned r = u + 0x7FFF + ((u >> 16) & 1);   // RNE
    return (unsigned short)(r >> 16);
}

__device__ __forceinline__ unsigned pack_half2(float a, float b) {
    __half2 h = __floats2half2_rn(a, b);
    return *reinterpret_cast<unsigned*>(&h);
}

// ---------------------------------------------------------------------------
// Merged prep: hist (records per-edge row slot), cvt_emb, cvt_wT, cvt_woT.
#define HIST_B 1954
#define EMB_B  2048
#define WT_B   128
#define WOT_B  64
__global__ __launch_bounds__(256) void prep_kernel(
    const float* __restrict__ entity, unsigned short* __restrict__ emb_bf,
    const float* __restrict__ W0, const float* __restrict__ W1,
    unsigned short* __restrict__ wT,
    const float* __restrict__ Wo, __half* __restrict__ woT,
    const int* __restrict__ eidx, int* __restrict__ counts,
    int* __restrict__ eoff)
{
    int bid = blockIdx.x;
    if (bid < HIST_B) {
        int e = bid * 256 + threadIdx.x;
        if (e < N_EDGE) eoff[e] = atomicAdd(&counts[eidx[e]], 1);
    } else if (bid < HIST_B + EMB_B) {
        int b = bid - HIST_B;
        const int nquads = N_ENT * 64 / 4;
        for (int i = b * 256 + threadIdx.x; i < nquads; i += EMB_B * 256) {
            float4 v = ((const float4*)entity)[i];
            ushort4 o;
            o.x = f2bf(v.x); o.y = f2bf(v.y); o.z = f2bf(v.z); o.w = f2bf(v.w);
            ((ushort4*)emb_bf)[i] = o;
        }
    } else if (bid < HIST_B + EMB_B + WT_B) {
        int idx = (bid - HIST_B - EMB_B) * 256 + threadIdx.x;   // 0..32767
        int mat = idx >> 14;
        int rem = idx & 16383;
        int col = rem >> 6;
        int k   = rem & 63;
        const float* W = (mat == 0) ? W0 : W1;
        wT[idx] = f2bf(W[k * 256 + col]);
    } else {
        int idx = (bid - HIST_B - EMB_B - WT_B) * 256 + threadIdx.x;  // 0..16383
        int d = idx >> 8;
        int k = idx & 255;
        woT[idx] = __float2half(Wo[k * 64 + d]);
    }
}

// ---------------------------------------------------------------------------
// MFMA attention projection, ONE mat per block. C layout (HW-verified):
// col=lane&15, row=(lane>>4)*4+reg.
__global__ __launch_bounds__(256) void proj_mfma_kernel(
    const unsigned short* __restrict__ emb_bf,   // [N][64] bf16
    const unsigned short* __restrict__ wT,       // [2*256][64] bf16
    const float* __restrict__ att0, const float* __restrict__ att1,
    float* __restrict__ p0, float* __restrict__ p1, int nrows, int nb)
{
    const int mat = (blockIdx.x >= nb) ? 1 : 0;
    const int rb  = blockIdx.x - mat * nb;
    const float* att = (mat == 0) ? att0 : att1;
    float* p         = (mat == 0) ? p0 : p1;
    const unsigned short* wbase = wT + (size_t)mat * 256 * 64;

    const int wv   = threadIdx.x >> 6;
    const int lane = threadIdx.x & 63;
    const int r4   = lane >> 4;
    const int cl   = lane & 15;
    const int rowbase = rb * 64 + wv * 16;

    int ra = min(rowbase + cl, nrows - 1);
    bf16x8 a0 = *(const bf16x8*)(emb_bf + (size_t)ra * 64 + 8 * r4);
    bf16x8 a1 = *(const bf16x8*)(emb_bf + (size_t)ra * 64 + 8 * r4 + 32);

    float pacc[4][4];   // [head][j]
#pragma unroll
    for (int head = 0; head < 4; ++head) {
        float vsum[4] = {0.f, 0.f, 0.f, 0.f};
#pragma unroll
        for (int sub = 0; sub < 4; ++sub) {
            int col = head * 64 + sub * 16 + cl;
            const unsigned short* wp = wbase + (size_t)col * 64 + 8 * r4;
            bf16x8 b0 = *(const bf16x8*)(wp);
            bf16x8 b1 = *(const bf16x8*)(wp + 32);
            f32x4 c = {0.f, 0.f, 0.f, 0.f};
            c = __builtin_amdgcn_mfma_f32_16x16x32_bf16(a0, b0, c, 0, 0, 0);
            c = __builtin_amdgcn_mfma_f32_16x16x32_bf16(a1, b1, c, 0, 0, 0);
            float av = att[head * 64 + sub * 16 + cl];
#pragma unroll
            for (int j = 0; j < 4; ++j)
                vsum[j] = fmaf(fast_tanh(c[j]), av, vsum[j]);
        }
#pragma unroll
        for (int j = 0; j < 4; ++j) {
            float v = vsum[j];
            v += __shfl_xor(v, 1, 64);
            v += __shfl_xor(v, 2, 64);
            v += __shfl_xor(v, 4, 64);
            v += __shfl_xor(v, 8, 64);
            pacc[head][j] = v;
        }
    }
    if (cl == 0) {
#pragma unroll
        for (int j = 0; j < 4; ++j) {
            int row = rowbase + r4 * 4 + j;
            if (row < nrows) {
                *(float4*)(p + (size_t)row * 4) = make_float4(
                    pacc[0][j], pacc[1][j], pacc[2][j], pacc[3][j]);
            }
        }
    }
}

// ---------------------------------------------------------------------------
// VALU projection for relations (only 200 rows).
__global__ __launch_bounds__(256) void proj_gemm_kernel(
    const float* __restrict__ emb,
    const float* __restrict__ W0,
    const float* __restrict__ att0,
    float* __restrict__ p0,
    int nrows)
{
    __shared__ float e_lds[64][68];
    __shared__ float w0_lds[64][64];
    __shared__ float red[4][4][64];

    const int t    = threadIdx.x;
    const int wv   = t >> 6;
    const int lane = t & 63;
    const int er   = t & 15;
    const int d0   = (t >> 4) * 4;
    const int base = blockIdx.x * 64;

#pragma unroll
    for (int i = 0; i < 4; ++i) {
        int f = t + 256 * i;
        int row = f >> 4, c4 = f & 15;
        int gr = min(base + row, nrows - 1);
        float4 v = *(const float4*)(emb + (size_t)gr * 64 + 4 * c4);
        *(float4*)&e_lds[row][4 * c4] = v;
    }

    float p0s[4][4];

    for (int head = 0; head < 4; ++head) {
        {
            int k0 = t >> 4, c4 = t & 15;
#pragma unroll
            for (int kk = 0; kk < 4; ++kk) {
                int k = k0 + 16 * kk;
                *(float4*)&w0_lds[k][4 * c4] =
                    *(const float4*)(W0 + (size_t)k * 256 + head * 64 + 4 * c4);
            }
        }
        __syncthreads();

        float acc0[4][4] = {};
        for (int k4 = 0; k4 < 16; ++k4) {
            float4 z0 = *(const float4*)&e_lds[er +  0][4 * k4];
            float4 z1 = *(const float4*)&e_lds[er + 16][4 * k4];
            float4 z2 = *(const float4*)&e_lds[er + 32][4 * k4];
            float4 z3 = *(const float4*)&e_lds[er + 48][4 * k4];
            const float zr[4][4] = {
                {z0.x, z0.y, z0.z, z0.w},
                {z1.x, z1.y, z1.z, z1.w},
                {z2.x, z2.y, z2.z, z2.w},
                {z3.x, z3.y, z3.z, z3.w}};
#pragma unroll
            for (int jj = 0; jj < 4; ++jj) {
                float4 w0v = *(const float4*)&w0_lds[4 * k4 + jj][d0];
#pragma unroll
                for (int i = 0; i < 4; ++i) {
                    float zj = zr[i][jj];
                    acc0[i][0] = fmaf(zj, w0v.x, acc0[i][0]);
                    acc0[i][1] = fmaf(zj, w0v.y, acc0[i][1]);
                    acc0[i][2] = fmaf(zj, w0v.z, acc0[i][2]);
                    acc0[i][3] = fmaf(zj, w0v.w, acc0[i][3]);
                }
            }
        }

        float4 av0 = *(const float4*)(att0 + head * 64 + d0);
#pragma unroll
        for (int i = 0; i < 4; ++i) {
            float v = fast_tanh(acc0[i][0]) * av0.x
                    + fast_tanh(acc0[i][1]) * av0.y
                    + fast_tanh(acc0[i][2]) * av0.z
                    + fast_tanh(acc0[i][3]) * av0.w;
            v += __shfl_xor(v, 16, 64);
            v += __shfl_xor(v, 32, 64);
            p0s[head][i] = v;
        }
        __syncthreads();
    }

    if (lane < 16) {
#pragma unroll
        for (int h = 0; h < 4; ++h)
#pragma unroll
            for (int i = 0; i < 4; ++i)
                red[wv][h][lane + 16 * i] = p0s[h][i];
    }
    __syncthreads();
    if (t < 64) {
        int row = base + t;
        if (row < nrows) {
            float4 pv;
            pv.x = red[0][0][t] + red[1][0][t] + red[2][0][t] + red[3][0][t];
            pv.y = red[0][1][t] + red[1][1][t] + red[2][1][t] + red[3][1][t];
            pv.z = red[0][2][t] + red[1][2][t] + red[2][2][t] + red[3][2][t];
            pv.w = red[0][3][t] + red[1][3][t] + red[2][3][t] + red[3][3][t];
            *(float4*)(p0 + (size_t)row * 4) = pv;
        }
    }
}

// ---------------------------------------------------------------------------
__global__ __launch_bounds__(1024) void scan_kernel(
    const int* __restrict__ counts, int* __restrict__ row_start)
{
    __shared__ int wsum[16];
    __shared__ int carry_s;
    const int lane = threadIdx.x & 63;
    const int wid  = threadIdx.x >> 6;
    if (threadIdx.x == 0) carry_s = 0;
    __syncthreads();
    for (int base = 0; base < N_ENT; base += 4096) {
        int i0 = base + (int)threadIdx.x * 4;
        int4 v = make_int4(0, 0, 0, 0);
        if (i0 + 3 < N_ENT) v = *(const int4*)(counts + i0);
        else {
            if (i0 + 0 < N_ENT) v.x = counts[i0 + 0];
            if (i0 + 1 < N_ENT) v.y = counts[i0 + 1];
            if (i0 + 2 < N_ENT) v.z = counts[i0 + 2];
            if (i0 + 3 < N_ENT) v.w = counts[i0 + 3];
        }
        int s1 = v.x + v.y, s2 = s1 + v.z, tsum = s2 + v.w;
        int incl = tsum;
#pragma unroll
        for (int off = 1; off < 64; off <<= 1) {
            int t = __shfl_up(incl, off, 64);
            if (lane >= off) incl += t;
        }
        if (lane == 63) wsum[wid] = incl;
        __syncthreads();                              // A
        int wave_off = 0;
#pragma unroll
        for (int w = 0; w < 16; ++w)
            wave_off += (w < wid) ? wsum[w] : 0;
        int carry = carry_s;
        int excl = carry + wave_off + (incl - tsum);
        if (i0 + 3 < N_ENT) {
            *(int4*)(row_start + i0) = make_int4(excl, excl + v.x, excl + s1, excl + s2);
        } else {
            if (i0 + 0 < N_ENT) row_start[i0 + 0] = excl;
            if (i0 + 1 < N_ENT) row_start[i0 + 1] = excl + v.x;
            if (i0 + 2 < N_ENT) row_start[i0 + 2] = excl + s1;
            if (i0 + 3 < N_ENT) row_start[i0 + 3] = excl + s2;
        }
        __syncthreads();                              // B
        if (threadIdx.x == 1023) carry_s = carry + wave_off + incl;
    }
    __syncthreads();
    if (threadIdx.x == 0) row_start[N_ENT] = carry_s;
}

// ---------------------------------------------------------------------------
// Per-edge scatter, NO atomics: slot precomputed in prep (eoff).
__global__ __launch_bounds__(256) void scatter_score_kernel(
    const int* __restrict__ eidx, const int* __restrict__ etype,
    const float* __restrict__ ph, const float* __restrict__ pt,
    const float* __restrict__ pr,
    const int* __restrict__ row_start, const int* __restrict__ eoff,
    int* __restrict__ csr_col, float* __restrict__ csr_a)
{
    int e = blockIdx.x * 256 + threadIdx.x;
    if (e >= N_EDGE) return;
    int hn = eidx[e];
    int tn = eidx[N_EDGE + e];
    int r  = etype[e];
    float4 a = *(const float4*)(ph + (size_t)hn * 4);
    float4 b = *(const float4*)(pt + (size_t)tn * 4);
    float4 c = *(const float4*)(pr + (size_t)r * 4);
    float s0 = a.x + b.x + c.x;
    float s1 = a.y + b.y + c.y;
    float s2 = a.z + b.z + c.z;
    float s3 = a.w + b.w + c.w;
    s0 = s0 >= 0.f ? s0 : 0.01f * s0;
    s1 = s1 >= 0.f ? s1 : 0.01f * s1;
    s2 = s2 >= 0.f ? s2 : 0.01f * s2;
    s3 = s3 >= 0.f ? s3 : 0.01f * s3;
    float4 ev = make_float4(__expf(s0), __expf(s1), __expf(s2), __expf(s3));
    int pos = row_start[hn] + eoff[e];
    csr_col[pos] = tn;
    *(float4*)(csr_a + (size_t)pos * 4) = ev;
}

// ---------------------------------------------------------------------------
// Pair-gather SpMM row body. lane = (half = lane>>5, j = lane&31); each
// 16B gather covers cols 8j..8j+7 of edge (e+half). Two banks (4 edges/iter).
// Odd-edge padding clamps to an already-gathered row (same cache lines ->
// no extra traffic) with zero multiplier. End: shfl_xor(32) combine.
// NORM: scale csr_a in-register and persist normalized values.
template <bool IN_HALF, bool NORM>
__device__ __forceinline__ void spmm_row_pair(
    int n, int lane, float scale,
    const __half* __restrict__ Zin_h, const float* __restrict__ emb,
    const int* __restrict__ row_start, const int* __restrict__ csr_col,
    float* __restrict__ csr_a, float acc[8])
{
    const int half = lane >> 5;
    const int j    = lane & 31;
    const int hd   = j >> 3;          // head of cols 8j..8j+7
    const int s    = row_start[n];
    const int end  = row_start[n + 1];

    {   // init: half 0 carries 0.1*z0 (emb cols 8*(j&7)..+7, head-broadcast)
        const float* z0p = emb + (size_t)n * 64 + 8 * (j & 7);
        float4 z0a = *(const float4*)(z0p);
        float4 z0b = *(const float4*)(z0p + 4);
        float m = (half == 0) ? 0.1f : 0.f;
        acc[0] = m * z0a.x; acc[1] = m * z0a.y; acc[2] = m * z0a.z; acc[3] = m * z0a.w;
        acc[4] = m * z0b.x; acc[5] = m * z0b.y; acc[6] = m * z0b.z; acc[7] = m * z0b.w;
    }
    float accB[8] = {0.f, 0.f, 0.f, 0.f, 0.f, 0.f, 0.f, 0.f};

    for (int b = s; b < end; b += 16) {
        const int nb = min(16, end - b);
        int   cl = (lane < nb) ? csr_col[b + lane] : 0;
        float al = (lane < nb * 4) ? csr_a[(size_t)b * 4 + lane] : 0.f;
        if (NORM) {
            al *= scale;                               // head lane&3
            if (lane < nb * 4) csr_a[(size_t)b * 4 + lane] = al;
        }
        for (int e = 0; e < nb; e += 4) {
            int iA = half ? min(e + 1, nb - 1) : e;
            int iB = half ? min(e + 3, nb - 1) : min(e + 2, nb - 1);
            int cA = __shfl(cl, iA, 64);
            int cB = __shfl(cl, iB, 64);
            float aA = __shfl(al, iA * 4 + hd, 64);
            float aB = __shfl(al, iB * 4 + hd, 64);
            aA = (e + half < nb) ? aA : 0.f;
            aB = (e + 2 + half < nb) ? aB : 0.f;
            if (IN_HALF) {
                f16x8 zA = *(const f16x8*)(Zin_h + (size_t)cA * 256 + 8 * j);
                f16x8 zB = *(const f16x8*)(Zin_h + (size_t)cB * 256 + 8 * j);
#pragma unroll
                for (int k = 0; k < 8; ++k) {
                    acc[k]  = fmaf(aA, (float)zA[k], acc[k]);
                    accB[k] = fmaf(aB, (float)zB[k], accB[k]);
                }
            } else {
                int ec = 8 * (j & 7);
                float4 zA0 = *(const float4*)(emb + (size_t)cA * 64 + ec);
                float4 zA1 = *(const float4*)(emb + (size_t)cA * 64 + ec + 4);
                float4 zB0 = *(const float4*)(emb + (size_t)cB * 64 + ec);
                float4 zB1 = *(const float4*)(emb + (size_t)cB * 64 + ec + 4);
                acc[0] = fmaf(aA, zA0.x, acc[0]);
                acc[1] = fmaf(aA, zA0.y, acc[1]);
                acc[2] = fmaf(aA, zA0.z, acc[2]);
                acc[3] = fmaf(aA, zA0.w, acc[3]);
                acc[4] = fmaf(aA, zA1.x, acc[4]);
                acc[5] = fmaf(aA, zA1.y, acc[5]);
                acc[6] = fmaf(aA, zA1.z, acc[6]);
                acc[7] = fmaf(aA, zA1.w, acc[7]);
                accB[0] = fmaf(aB, zB0.x, accB[0]);
                accB[1] = fmaf(aB, zB0.y, accB[1]);
                accB[2] = fmaf(aB, zB0.z, accB[2]);
                accB[3] = fmaf(aB, zB0.w, accB[3]);
                accB[4] = fmaf(aB, zB1.x, accB[4]);
                accB[5] = fmaf(aB, zB1.y, accB[5]);
                accB[6] = fmaf(aB, zB1.z, accB[6]);
                accB[7] = fmaf(aB, zB1.w, accB[7]);
            }
        }
    }
#pragma unroll
    for (int k = 0; k < 8; ++k) {
        float v = acc[k] + accB[k];
        v += __shfl_xor(v, 32, 64);
        acc[k] = v;
    }
}

__device__ __forceinline__ void store_row_h(
    __half* __restrict__ dst256, int lane, const float acc[8])
{
    if (lane < 32) {
        uint4 o;
        o.x = pack_half2(acc[0], acc[1]);
        o.y = pack_half2(acc[2], acc[3]);
        o.z = pack_half2(acc[4], acc[5]);
        o.w = pack_half2(acc[6], acc[7]);
        *(uint4*)(dst256 + 8 * lane) = o;
    }
}

// ---------------------------------------------------------------------------
// Fused softmax-normalize + first SpMM. Wave per row.
__global__ __launch_bounds__(256) void norm_spmm1_kernel(
    const float* __restrict__ emb,
    const int* __restrict__ row_start, const int* __restrict__ csr_col,
    float* __restrict__ csr_a, __half* __restrict__ Zout)
{
    const int wave = threadIdx.x >> 6;
    const int lane = threadIdx.x & 63;
    const int n = blockIdx.x * 4 + wave;
    const int s   = row_start[n];
    const int end = row_start[n + 1];
    const int nf  = (end - s) * 4;

    float sum = 0.f;
    for (int f = lane; f < nf; f += 64)
        sum += csr_a[(size_t)s * 4 + f];
#pragma unroll
    for (int off = 4; off < 64; off <<= 1)
        sum += __shfl_xor(sum, off, 64);
    float scale = 0.9f * __builtin_amdgcn_rcpf(sum + 1e-16f);  // head lane&3

    float acc[8];
    spmm_row_pair<false, true>(n, lane, scale, nullptr, emb,
                               row_start, csr_col, csr_a, acc);
    store_row_h(Zout + (size_t)n * 256, lane, acc);
}

// ---------------------------------------------------------------------------
// Standalone SpMM step (iterations 2..4).
__global__ __launch_bounds__(256) void spmm_kernel(
    const __half* __restrict__ Zin, const float* __restrict__ emb,
    const int* __restrict__ row_start, const int* __restrict__ csr_col,
    float* __restrict__ csr_a, __half* __restrict__ Zout)
{
    const int wave = threadIdx.x >> 6;
    const int lane = threadIdx.x & 63;
    const int n = blockIdx.x * 4 + wave;
    float acc[8];
    spmm_row_pair<true, false>(n, lane, 1.f, Zin, emb,
                               row_start, csr_col, csr_a, acc);
    store_row_h(Zout + (size_t)n * 256, lane, acc);
}

// ---------------------------------------------------------------------------
// Fused: 5th SpMM + output projection. Block = 16 rows.
__global__ __launch_bounds__(256) void spmm_out_fused_kernel(
    const __half* __restrict__ Zin, const float* __restrict__ emb,
    const int* __restrict__ row_start, const int* __restrict__ csr_col,
    float* __restrict__ csr_a,
    const __half* __restrict__ woT,    // [64][256] fp16 (d-major)
    float* __restrict__ out)           // [N][64]
{
    __shared__ _Float16 zl[16][264];
    const int wv   = threadIdx.x >> 6;
    const int lane = threadIdx.x & 63;
    const int base = blockIdx.x * 16;

#pragma unroll
    for (int rr = 0; rr < 4; ++rr) {
        int n = base + wv * 4 + rr;
        float acc[8];
        spmm_row_pair<true, false>(n, lane, 1.f, Zin, emb,
                                   row_start, csr_col, csr_a, acc);
        if (lane < 32) {
            uint4 o;
            o.x = pack_half2(acc[0], acc[1]);
            o.y = pack_half2(acc[2], acc[3]);
            o.z = pack_half2(acc[4], acc[5]);
            o.w = pack_half2(acc[6], acc[7]);
            *(uint4*)&zl[wv * 4 + rr][8 * lane] = o;
        }
    }
    __syncthreads();

    const int cl = lane & 15;
    const int r4 = lane >> 4;
    f16x8 a[8];
#pragma unroll
    for (int ks = 0; ks < 8; ++ks)
        a[ks] = *(const f16x8*)&zl[cl][ks * 32 + 8 * r4];

    const _Float16* wcol = (const _Float16*)woT + (size_t)(wv * 16 + cl) * 256 + 8 * r4;
    f32x4 c = {0.f, 0.f, 0.f, 0.f};
#pragma unroll
    for (int ks = 0; ks < 8; ++ks) {
        f16x8 b = *(const f16x8*)(wcol + ks * 32);
        c = __builtin_amdgcn_mfma_f32_16x16x32_f16(a[ks], b, c, 0, 0, 0);
    }
#pragma unroll
    for (int j = 0; j < 4; ++j) {
        int row = base + r4 * 4 + j;
        out[(size_t)row * 64 + wv * 16 + cl] = c[j];
    }
}

// ---------------------------------------------------------------------------
extern "C" void kernel_launch(void* const* d_in, const int* in_sizes, int n_in,
                              void* d_out, int out_size, void* d_ws, size_t ws_size,
                              hipStream_t stream)
{
    const float* entity = (const float*)d_in[0];
    const float* rel    = (const float*)d_in[1];
    const float* W_h    = (const float*)d_in[2];
    const float* W_t    = (const float*)d_in[3];
    const float* W_r    = (const float*)d_in[4];
    const float* att_h  = (const float*)d_in[5];
    const float* att_t  = (const float*)d_in[6];
    const float* att_r  = (const float*)d_in[7];
    const float* W_o    = (const float*)d_in[8];
    const int*   eidx   = (const int*)d_in[9];   // [2,E]
    const int*   etype  = (const int*)d_in[10];  // [E]
    float* out = (float*)d_out;

    char* ws = (char*)d_ws;
    size_t off = 0;
    auto alloc = [&](size_t bytes) -> void* {
        void* p = ws + off;
        off += (bytes + 255) & ~(size_t)255;
        return p;
    };
    float* p_h      = (float*)alloc((size_t)N_ENT * 4 * 4);
    float* p_t      = (float*)alloc((size_t)N_ENT * 4 * 4);
    float* p_r      = (float*)alloc((size_t)N_REL * 4 * 4);
    int*   counts   = (int*)alloc((size_t)N_ENT * 4);
    int*   row_start= (int*)alloc(((size_t)N_ENT + 1) * 4);
    int*   eoff     = (int*)alloc((size_t)N_EDGE * 4);
    int*   csr_col  = (int*)alloc((size_t)N_EDGE * 4);
    float* csr_a    = (float*)alloc((size_t)N_EDGE * 4 * 4);
    __half* Zh_a    = (__half*)alloc((size_t)N_ENT * 256 * 2);
    __half* Zh_b    = (__half*)alloc((size_t)N_ENT * 256 * 2);
    unsigned short* emb_bf = (unsigned short*)alloc((size_t)N_ENT * 64 * 2);
    unsigned short* wT     = (unsigned short*)alloc((size_t)2 * 256 * 64 * 2);
    __half* woT     = (__half*)alloc((size_t)64 * 256 * 2);

    hipMemsetAsync(counts, 0, (size_t)N_ENT * 4, stream);

    // merged prep: hist (+slot record) + bf16/fp16 conversions
    prep_kernel<<<HIST_B + EMB_B + WT_B + WOT_B, 256, 0, stream>>>(
        entity, emb_bf, W_h, W_t, wT, W_o, woT, eidx, counts, eoff);

    // projections: h/t via MFMA (mat-split grid), relations via VALU
    const int nb = (N_ENT + 63) / 64;
    proj_mfma_kernel<<<2 * nb, 256, 0, stream>>>(
        emb_bf, wT, att_h, att_t, p_h, p_t, N_ENT, nb);
    proj_gemm_kernel<<<(N_REL + 63) / 64, 256, 0, stream>>>(
        rel, W_r, att_r, p_r, N_REL);

    scan_kernel<<<1, 1024, 0, stream>>>(counts, row_start);
    scatter_score_kernel<<<(N_EDGE + 255) / 256, 256, 0, stream>>>(
        eidx, etype, p_h, p_t, p_r, row_start, eoff, csr_col, csr_a);

    // power iteration: normalize fused with Z1; Z2..Z4 standalone;
    // Z5 fused with output projection
    norm_spmm1_kernel<<<N_ENT / 4, 256, 0, stream>>>(
        entity, row_start, csr_col, csr_a, Zh_b);
    spmm_kernel<<<N_ENT / 4, 256, 0, stream>>>(Zh_b, entity, row_start, csr_col, csr_a, Zh_a);
    spmm_kernel<<<N_ENT / 4, 256, 0, stream>>>(Zh_a, entity, row_start, csr_col, csr_a, Zh_b);
    spmm_kernel<<<N_ENT / 4, 256, 0, stream>>>(Zh_b, entity, row_start, csr_col, csr_a, Zh_a);
    spmm_out_fused_kernel<<<N_ENT / 16, 256, 0, stream>>>(
        Zh_a, entity, row_start, csr_col, csr_a, woT, out);
}